// Round 9
// baseline (324.769 us; speedup 1.0000x reference)
//
#include <hip/hip_runtime.h>
#include <stdint.h>

typedef unsigned short ushort_t;
typedef __attribute__((__ext_vector_type__(8))) __bf16 bf16x8;
typedef __attribute__((__ext_vector_type__(4))) float f32x4;

__device__ inline ushort_t f2bf(float f) {
    unsigned int u = __float_as_uint(f);
    u = u + 0x7FFFu + ((u >> 16) & 1u);
    return (ushort_t)(u >> 16);
}
__device__ inline float bf2f(ushort_t h) {
    return __uint_as_float(((unsigned int)h) << 16);
}
__device__ inline unsigned pack2(float a, float b) {
    return (unsigned)f2bf(a) | ((unsigned)f2bf(b) << 16);
}

#define GLOAD16(gp, lp) __builtin_amdgcn_global_load_lds( \
    (__attribute__((address_space(1))) void*)(gp),        \
    (__attribute__((address_space(3))) void*)(lp), 16, 0, 0)

// =====================================================================
// NT GEMM: C[M,N] = A[M,K] * B[N,K]^T. BM=128, BK=32, 256 thr = 4 waves.
// XCD-chunked block swizzle (grids multiples of 8).
// STG 0: A bf16 via global_load_lds (r4-proven 2-barrier loop).
// STG 1: A f32 -> bf16 fused convert, reg-staged.       [QKV proj]
// STG 2: A = E bf16, P = E*inv + I(f32), reg-staged.    [PV fused]
// STG!=0 loop = EXACTLY the r5 passing structure (single fixed LDS
// buffers, storeA ; gloadB ; bar1 ; mfma ; bar2) with ONE change:
// loadA(next) is issued after bar1 (register-only op) so its latency is
// covered by the MFMA phase instead of being drained cold at bar1.
// NO runtime-indexed LDS bases anywhere (r7/r8 corruption source).
// MODE 0: C bf16 (+opt bias) | MODE 3: C f32 + bias
// MODE 4: QKV split epilogue | MODE 5: C=exp(v*scale) bf16 + atomic rowsum
// =====================================================================
template<int MODE, int BN, int BK, int STG>
__global__ __launch_bounds__(256)
void gemm_nt(const void* __restrict__ Av, const ushort_t* __restrict__ B,
             void* __restrict__ Cv, const float* __restrict__ bias,
             const float* __restrict__ If, const float* __restrict__ invp,
             int K, int lda, int ldb, int ldc, float scale,
             long long sA, long long sB, long long sC,
             float* __restrict__ rsum)
{
    constexpr int WN  = BN / 2;
    constexpr int NR  = WN / 16;
    constexpr int GPR = BK / 8;
    constexpr int AG  = 128 * GPR;
    constexpr int BG  = BN * GPR;
    __shared__ __align__(16) char lds[(128 + BN) * BK * 2];
    char* ldsA = lds;
    char* ldsB = lds + 128 * BK * 2;

    const int t = threadIdx.x;

    // ---- XCD-chunked swizzle ----
    const int gx = gridDim.x, gy = gridDim.y;
    const int nwg = gx * gy * gridDim.z;
    int h = (blockIdx.z * gy + blockIdx.y) * gx + blockIdx.x;
    int logical = (h & 7) * (nwg >> 3) + (h >> 3);
    const int bx = logical % gx;
    const int tmp = logical / gx;
    const int by = tmp % gy;
    const int z  = tmp / gy;

    const ushort_t* A = (const ushort_t*)Av + (size_t)z * (size_t)sA;
    const float* Af   = (const float*)Av + (size_t)z * (size_t)sA;
    const float* Iz   = If ? If + (size_t)z * (size_t)sA : nullptr;
    const float* invz = invp ? invp + (size_t)z * 2048 : nullptr;
    B += (size_t)z * (size_t)sB;

    const int rowBase = by * 128;
    const int colBase = bx * BN;

    const int w    = t >> 6;
    const int lane = t & 63;
    const int wr = w >> 1, wc = w & 1;
    const int lr = lane & 15, lg = lane >> 4;

    f32x4 acc[4][NR];
#pragma unroll
    for (int i = 0; i < 4; ++i)
#pragma unroll
        for (int j = 0; j < NR; ++j)
            acc[i][j] = (f32x4){0.f, 0.f, 0.f, 0.f};

    // ---- A prefetch registers (STG 1/2) ----
    float4 xR[4];                       // STG 1
    uint4  eR[2]; float4 iA[2], iB[2];  // STG 2
    float  invR[2];

    auto loadA = [&](int kt) {
        if constexpr (STG == 1) {
#pragma unroll
            for (int i = 0; i < 2; ++i) {
                const int L = i * 256 + t, row = L >> 2, g = L & 3;
                const float* xp = Af + (size_t)(rowBase + row) * (size_t)lda + kt + g * 8;
                xR[2 * i]     = *(const float4*)xp;
                xR[2 * i + 1] = *(const float4*)(xp + 4);
            }
        } else if constexpr (STG == 2) {
#pragma unroll
            for (int i = 0; i < 2; ++i) {
                const int L = i * 256 + t, row = L >> 2, g = L & 3;
                const ushort_t* ep = A + (size_t)(rowBase + row) * (size_t)lda + kt + g * 8;
                eR[i] = *(const uint4*)ep;
                const float* ip = Iz + (size_t)(rowBase + row) * (size_t)lda + kt + g * 8;
                iA[i] = *(const float4*)ip;
                iB[i] = *(const float4*)(ip + 4);
                invR[i] = invz[rowBase + row];
            }
        }
    };
    auto storeA = [&]() {
#pragma unroll
        for (int i = 0; i < 2; ++i) {
            const int L = i * 256 + t;
            uint4 o;
            if constexpr (STG == 1) {
                o.x = pack2(xR[2*i].x, xR[2*i].y);
                o.y = pack2(xR[2*i].z, xR[2*i].w);
                o.z = pack2(xR[2*i+1].x, xR[2*i+1].y);
                o.w = pack2(xR[2*i+1].z, xR[2*i+1].w);
            } else {
                union { ushort_t hh[8]; uint4 u; } e; e.u = eR[i];
                const float iv = invR[i];
                o.x = pack2(bf2f(e.hh[0]) * iv + iA[i].x, bf2f(e.hh[1]) * iv + iA[i].y);
                o.y = pack2(bf2f(e.hh[2]) * iv + iA[i].z, bf2f(e.hh[3]) * iv + iA[i].w);
                o.z = pack2(bf2f(e.hh[4]) * iv + iB[i].x, bf2f(e.hh[5]) * iv + iB[i].y);
                o.w = pack2(bf2f(e.hh[6]) * iv + iB[i].z, bf2f(e.hh[7]) * iv + iB[i].w);
            }
            *(uint4*)(ldsA + (size_t)L * 16) = o;
        }
    };

    if constexpr (STG != 0) loadA(0);

    for (int kt = 0; kt < K; kt += BK) {
        if constexpr (STG == 0) {
#pragma unroll
            for (int i = 0; i < AG / 256; ++i) {
                const int L = i * 256 + t;
                const int row = L / GPR, g = L % GPR;
                GLOAD16(A + (size_t)(rowBase + row) * (size_t)lda + (kt + g * 8),
                        ldsA + L * 16);
            }
        } else {
            storeA();
        }
#pragma unroll
        for (int i = 0; i < BG / 256; ++i) {
            const int L = i * 256 + t;
            const int row = L / GPR, g = L % GPR;
            GLOAD16(B + (size_t)(colBase + row) * (size_t)ldb + (kt + g * 8),
                    ldsB + L * 16);
        }
        __syncthreads();
        // issue next-tile A register loads AFTER the barrier: latency is
        // covered by the MFMA phase, drained cheaply at the second barrier.
        if constexpr (STG != 0) { if (kt + BK < K) loadA(kt + BK); }

        const bf16x8* A8 = (const bf16x8*)ldsA;
        const bf16x8* B8 = (const bf16x8*)ldsB;
#pragma unroll
        for (int kk = 0; kk < BK / 32; ++kk) {
            bf16x8 af[4], bq[NR];
#pragma unroll
            for (int mi = 0; mi < 4; ++mi)
                af[mi] = A8[(wr * 64 + mi * 16 + lr) * GPR + kk * 4 + lg];
#pragma unroll
            for (int ni = 0; ni < NR; ++ni)
                bq[ni] = B8[(wc * WN + ni * 16 + lr) * GPR + kk * 4 + lg];
#pragma unroll
            for (int mi = 0; mi < 4; ++mi)
#pragma unroll
                for (int ni = 0; ni < NR; ++ni)
                    acc[mi][ni] = __builtin_amdgcn_mfma_f32_16x16x32_bf16(
                        af[mi], bq[ni], acc[mi][ni], 0, 0, 0);
        }
        __syncthreads();
    }

    // ---- epilogue ----
    float rs[4][4];
    if (MODE == 5) {
#pragma unroll
        for (int mi = 0; mi < 4; ++mi)
#pragma unroll
            for (int r = 0; r < 4; ++r) rs[mi][r] = 0.f;
    }

#pragma unroll
    for (int mi = 0; mi < 4; ++mi) {
#pragma unroll
        for (int ni = 0; ni < NR; ++ni) {
#pragma unroll
            for (int r = 0; r < 4; ++r) {
                const int grow = rowBase + wr * 64 + mi * 16 + lg * 4 + r;
                const int gcol = colBase + wc * WN + ni * 16 + lr;
                float v = acc[mi][ni][r] * scale;
                if (MODE == 0) {
                    if (bias) v += bias[gcol];
                    ushort_t* C = (ushort_t*)Cv + (size_t)z * (size_t)sC;
                    C[(size_t)grow * (size_t)ldc + gcol] = f2bf(v);
                } else if (MODE == 3) {
                    float* C = (float*)Cv;
                    C[(size_t)grow * (size_t)ldc + gcol] = v + bias[gcol];
                } else if (MODE == 4) {
                    v += bias[gcol];
                    const int seg = gcol >> 9, c = gcol & 511;
                    ushort_t* C = (ushort_t*)Cv;
                    C[(size_t)seg * 8388608 + (size_t)grow * 512 + c] = f2bf(v);
                } else { // MODE 5
                    float e = __expf(v);
                    ushort_t* C = (ushort_t*)Cv + (size_t)z * (size_t)sC;
                    C[(size_t)grow * (size_t)ldc + gcol] = f2bf(e);
                    rs[mi][r] += e;
                }
            }
        }
    }

    if (MODE == 5) {
#pragma unroll
        for (int mi = 0; mi < 4; ++mi) {
#pragma unroll
            for (int r = 0; r < 4; ++r) {
                float s = rs[mi][r];
                s += __shfl_xor(s, 1);
                s += __shfl_xor(s, 2);
                s += __shfl_xor(s, 4);
                s += __shfl_xor(s, 8);
                if (lr == 0) {
                    const int grow = rowBase + wr * 64 + mi * 16 + lg * 4 + r;
                    atomicAdd(&rsum[z * 2048 + grow], s);
                }
            }
        }
    }
}

// =====================================================================
// V [8][2048][512] -> Vt [8][512][2048]
// =====================================================================
__global__ __launch_bounds__(256)
void transpose_v(const ushort_t* __restrict__ V, ushort_t* __restrict__ Vt)
{
    __shared__ ushort_t lds[64][68];
    const int t = threadIdx.x;
    const int nBase = blockIdx.x * 64;
    const int dBase = blockIdx.y * 64;
    const size_t b = blockIdx.z;
    const ushort_t* src = V + b * 1048576;
    ushort_t* dst = Vt + b * 1048576;
#pragma unroll
    for (int i = 0; i < 2; ++i) {
        int s = i * 256 + t;
        int n = s >> 3, dg = s & 7;
        union { ushort_t h[8]; uint4 u; } p;
        p.u = *(const uint4*)(src + (size_t)(nBase + n) * 512 + dBase + dg * 8);
#pragma unroll
        for (int j = 0; j < 8; ++j) lds[n][dg * 8 + j] = p.h[j];
    }
    __syncthreads();
#pragma unroll
    for (int i = 0; i < 2; ++i) {
        int s = i * 256 + t;
        int d = s >> 3, ng = s & 7;
        union { ushort_t h[8]; uint4 u; } p;
#pragma unroll
        for (int j = 0; j < 8; ++j) p.h[j] = lds[ng * 8 + j][d];
        *(uint4*)(dst + (size_t)(dBase + d) * 2048 + nBase + ng * 8) = p.u;
    }
}

// =====================================================================
__global__ __launch_bounds__(256)
void cvt_bf16(const float* __restrict__ src, ushort_t* __restrict__ dst, int n4)
{
    int i = blockIdx.x * 256 + threadIdx.x;
    if (i >= n4) return;
    float4 v = ((const float4*)src)[i];
    union { ushort_t h[4]; uint2 u; } p;
    p.h[0] = f2bf(v.x); p.h[1] = f2bf(v.y); p.h[2] = f2bf(v.z); p.h[3] = f2bf(v.w);
    ((uint2*)dst)[i] = p.u;
}

__global__ __launch_bounds__(256)
void pack_bias(const float* __restrict__ q, const float* __restrict__ k,
               const float* __restrict__ v, float* __restrict__ dst)
{
    int i = blockIdx.x * 256 + threadIdx.x;
    if (i < 512) dst[i] = q[i];
    else if (i < 1024) dst[i] = k[i - 512];
    else if (i < 1536) dst[i] = v[i - 1024];
}

__global__ __launch_bounds__(256)
void zero_f32(float* __restrict__ p, int n)
{
    int i = blockIdx.x * 256 + threadIdx.x;
    if (i < n) p[i] = 0.f;
}

__global__ __launch_bounds__(256)
void recip_f32(float* __restrict__ p, int n)
{
    int i = blockIdx.x * 256 + threadIdx.x;
    if (i < n) p[i] = 1.0f / p[i];
}

// =====================================================================
extern "C" void kernel_launch(void* const* d_in, const int* in_sizes, int n_in,
                              void* d_out, int out_size, void* d_ws, size_t ws_size,
                              hipStream_t stream)
{
    const float* X    = (const float*)d_in[0];
    const float* inten= (const float*)d_in[1];
    const float* WQw  = (const float*)d_in[2];
    const float* WQb  = (const float*)d_in[3];
    const float* WKw  = (const float*)d_in[4];
    const float* WKb  = (const float*)d_in[5];
    const float* WVw  = (const float*)d_in[6];
    const float* WVb  = (const float*)d_in[7];
    const float* Wow  = (const float*)d_in[8];
    const float* Wob  = (const float*)d_in[9];
    float* out = (float*)d_out;

    char* ws = (char*)d_ws;
    ushort_t* Vt    = (ushort_t*)(ws + 0);           // 16 MiB
    ushort_t* Wqkv  = (ushort_t*)(ws + 16777216);    // 1536x512 bf16
    ushort_t* Wob2  = (ushort_t*)(ws + 18350080);    // 512x512 bf16
    float*    biasP = (float*)   (ws + 18874368);    // 1536 f32
    float*    rowsum= (float*)   (ws + 18882560);    // 16384 f32
    ushort_t* QKV   = (ushort_t*)(ws + 19922944);    // Q|K|V row-major, 3x16 MiB
    ushort_t* out1  = (ushort_t*)(ws + 70254592);    // 16 MiB
    ushort_t* Sbf   = (ushort_t*)(ws + 87031808);    // E bf16, 64 MiB
    ushort_t* Qb  = QKV;
    ushort_t* Kb  = QKV + 8388608;
    ushort_t* Vrm = QKV + 16777216;

    const float scale = 0.044194173824159216f;       // 1/sqrt(512)

    cvt_bf16<<<dim3(256), dim3(256), 0, stream>>>(WQw, Wqkv,          65536);
    cvt_bf16<<<dim3(256), dim3(256), 0, stream>>>(WKw, Wqkv + 262144, 65536);
    cvt_bf16<<<dim3(256), dim3(256), 0, stream>>>(WVw, Wqkv + 524288, 65536);
    cvt_bf16<<<dim3(256), dim3(256), 0, stream>>>(Wow, Wob2,          65536);
    pack_bias<<<dim3(6), dim3(256), 0, stream>>>(WQb, WKb, WVb, biasP);
    zero_f32<<<dim3(64), dim3(256), 0, stream>>>(rowsum, 16384);

    // fused QKV projection (A = f32 X, converted during reg-staging)
    gemm_nt<4, 128, 32, 1><<<dim3(12, 128, 1), dim3(256), 0, stream>>>(
        X, Wqkv, QKV, biasP, nullptr, nullptr,
        512, 512, 512, 0, 1.f, 0, 0, 0, nullptr);

    // Vt[b][d][n] = V[b][n][d]
    transpose_v<<<dim3(32, 8, 8), dim3(256), 0, stream>>>(Vrm, Vt);

    // E = exp(scale * Q K^T) bf16 + f32 row sums (atomics)
    gemm_nt<5, 128, 32, 0><<<dim3(16, 16, 8), dim3(256), 0, stream>>>(
        Qb, Kb, Sbf, nullptr, nullptr, nullptr,
        512, 512, 512, 2048, scale,
        2048LL * 512, 2048LL * 512, 2048LL * 2048, rowsum);

    // rowsum -> 1/rowsum
    recip_f32<<<dim3(64), dim3(256), 0, stream>>>(rowsum, 16384);

    // out1 = (E*inv + I) @ Vt^T per batch, normalize+intensity fused in staging
    gemm_nt<0, 64, 32, 2><<<dim3(8, 16, 8), dim3(256), 0, stream>>>(
        Sbf, Vt, out1, nullptr, inten, rowsum,
        2048, 2048, 2048, 512, 1.f,
        2048LL * 2048, 512LL * 2048, 2048LL * 512, nullptr);

    // out = out1 @ Wo^T + bo  [16384,512] f32
    gemm_nt<3, 64, 32, 0><<<dim3(8, 128, 1), dim3(256), 0, stream>>>(
        out1, Wob2, out, Wob, nullptr, nullptr,
        512, 512, 512, 512, 1.f, 0, 0, 0, nullptr);
}

// Round 10
// 265.696 us; speedup vs baseline: 1.2223x; 1.2223x over previous
//
#include <hip/hip_runtime.h>
#include <stdint.h>

typedef unsigned short ushort_t;
typedef __attribute__((__ext_vector_type__(8))) __bf16 bf16x8;
typedef __attribute__((__ext_vector_type__(4))) float f32x4;

__device__ inline ushort_t f2bf(float f) {
    unsigned int u = __float_as_uint(f);
    u = u + 0x7FFFu + ((u >> 16) & 1u);
    return (ushort_t)(u >> 16);
}
__device__ inline float bf2f(ushort_t h) {
    return __uint_as_float(((unsigned int)h) << 16);
}

#define GLOAD16(gp, lp) __builtin_amdgcn_global_load_lds( \
    (__attribute__((address_space(1))) void*)(gp),        \
    (__attribute__((address_space(3))) void*)(lp), 16, 0, 0)

// =====================================================================
// NT GEMM: C[M,N] = A[M,K] * B[N,K]^T  (A,B bf16-as-ushort)
// BM=128, BN in {128,64}, BK=32. 256 thr = 4 waves (2x2),
// wave tile 64 x (BN/2). MFMA 16x16x32 bf16. r4-proven STG0 loop only.
// XCD-chunked block swizzle (grids multiples of 8).
// MODE 0: C bf16 (+opt bias) | MODE 3: C f32 + bias
// MODE 4: QKV split epilogue (3 row-major [16384,512] outputs)
// MODE 5: C = exp(v*scale) bf16 + f32 atomic row sums (r9-proven)
// =====================================================================
template<int MODE, int BN, int BK>
__global__ __launch_bounds__(256)
void gemm_nt(const ushort_t* __restrict__ A, const ushort_t* __restrict__ B,
             void* __restrict__ Cv, const float* __restrict__ bias,
             int K, int lda, int ldb, int ldc, float scale,
             long long sA, long long sB, long long sC,
             float* __restrict__ rsum)
{
    constexpr int WN  = BN / 2;
    constexpr int NR  = WN / 16;
    constexpr int GPR = BK / 8;
    constexpr int AG  = 128 * GPR;
    constexpr int BG  = BN * GPR;
    __shared__ __align__(16) char lds[(128 + BN) * BK * 2];
    char* ldsA = lds;
    char* ldsB = lds + 128 * BK * 2;

    const int t = threadIdx.x;

    // ---- XCD-chunked swizzle ----
    const int gx = gridDim.x, gy = gridDim.y;
    const int nwg = gx * gy * gridDim.z;
    int h = (blockIdx.z * gy + blockIdx.y) * gx + blockIdx.x;
    int logical = (h & 7) * (nwg >> 3) + (h >> 3);
    const int bx = logical % gx;
    const int tmp = logical / gx;
    const int by = tmp % gy;
    const int z  = tmp / gy;

    A += (size_t)z * (size_t)sA;
    B += (size_t)z * (size_t)sB;

    const int rowBase = by * 128;
    const int colBase = bx * BN;

    const int w    = t >> 6;
    const int lane = t & 63;
    const int wr = w >> 1, wc = w & 1;
    const int lr = lane & 15, lg = lane >> 4;

    f32x4 acc[4][NR];
#pragma unroll
    for (int i = 0; i < 4; ++i)
#pragma unroll
        for (int j = 0; j < NR; ++j)
            acc[i][j] = (f32x4){0.f, 0.f, 0.f, 0.f};

    for (int kt = 0; kt < K; kt += BK) {
#pragma unroll
        for (int i = 0; i < AG / 256; ++i) {
            const int L = i * 256 + t;
            const int row = L / GPR, g = L % GPR;
            GLOAD16(A + (size_t)(rowBase + row) * (size_t)lda + (kt + g * 8),
                    ldsA + L * 16);
        }
#pragma unroll
        for (int i = 0; i < BG / 256; ++i) {
            const int L = i * 256 + t;
            const int row = L / GPR, g = L % GPR;
            GLOAD16(B + (size_t)(colBase + row) * (size_t)ldb + (kt + g * 8),
                    ldsB + L * 16);
        }
        __syncthreads();

        const bf16x8* A8 = (const bf16x8*)ldsA;
        const bf16x8* B8 = (const bf16x8*)ldsB;
#pragma unroll
        for (int kk = 0; kk < BK / 32; ++kk) {
            bf16x8 af[4], bq[NR];
#pragma unroll
            for (int mi = 0; mi < 4; ++mi)
                af[mi] = A8[(wr * 64 + mi * 16 + lr) * GPR + kk * 4 + lg];
#pragma unroll
            for (int ni = 0; ni < NR; ++ni)
                bq[ni] = B8[(wc * WN + ni * 16 + lr) * GPR + kk * 4 + lg];
#pragma unroll
            for (int mi = 0; mi < 4; ++mi)
#pragma unroll
                for (int ni = 0; ni < NR; ++ni)
                    acc[mi][ni] = __builtin_amdgcn_mfma_f32_16x16x32_bf16(
                        af[mi], bq[ni], acc[mi][ni], 0, 0, 0);
        }
        __syncthreads();
    }

    // ---- epilogue ----
    float rs[4][4];
    if (MODE == 5) {
#pragma unroll
        for (int mi = 0; mi < 4; ++mi)
#pragma unroll
            for (int r = 0; r < 4; ++r) rs[mi][r] = 0.f;
    }

#pragma unroll
    for (int mi = 0; mi < 4; ++mi) {
#pragma unroll
        for (int ni = 0; ni < NR; ++ni) {
#pragma unroll
            for (int r = 0; r < 4; ++r) {
                const int grow = rowBase + wr * 64 + mi * 16 + lg * 4 + r;
                const int gcol = colBase + wc * WN + ni * 16 + lr;
                float v = acc[mi][ni][r] * scale;
                if (MODE == 0) {
                    if (bias) v += bias[gcol];
                    ushort_t* C = (ushort_t*)Cv + (size_t)z * (size_t)sC;
                    C[(size_t)grow * (size_t)ldc + gcol] = f2bf(v);
                } else if (MODE == 3) {
                    float* C = (float*)Cv;
                    C[(size_t)grow * (size_t)ldc + gcol] = v + bias[gcol];
                } else if (MODE == 4) {
                    v += bias[gcol];
                    const int seg = gcol >> 9, c = gcol & 511;
                    ushort_t* C = (ushort_t*)Cv;
                    C[(size_t)seg * 8388608 + (size_t)grow * 512 + c] = f2bf(v);
                } else { // MODE 5
                    float e = __expf(v);
                    ushort_t* C = (ushort_t*)Cv + (size_t)z * (size_t)sC;
                    C[(size_t)grow * (size_t)ldc + gcol] = f2bf(e);
                    rs[mi][r] += e;
                }
            }
        }
    }

    if (MODE == 5) {
#pragma unroll
        for (int mi = 0; mi < 4; ++mi) {
#pragma unroll
            for (int r = 0; r < 4; ++r) {
                float s = rs[mi][r];
                s += __shfl_xor(s, 1);
                s += __shfl_xor(s, 2);
                s += __shfl_xor(s, 4);
                s += __shfl_xor(s, 8);
                if (lr == 0) {
                    const int grow = rowBase + wr * 64 + mi * 16 + lg * 4 + r;
                    atomicAdd(&rsum[z * 2048 + grow], s);
                }
            }
        }
    }
}

// =====================================================================
// V [8][2048][512] -> Vt [8][512][2048]
// =====================================================================
__global__ __launch_bounds__(256)
void transpose_v(const ushort_t* __restrict__ V, ushort_t* __restrict__ Vt)
{
    __shared__ ushort_t lds[64][68];
    const int t = threadIdx.x;
    const int nBase = blockIdx.x * 64;
    const int dBase = blockIdx.y * 64;
    const size_t b = blockIdx.z;
    const ushort_t* src = V + b * 1048576;
    ushort_t* dst = Vt + b * 1048576;
#pragma unroll
    for (int i = 0; i < 2; ++i) {
        int s = i * 256 + t;
        int n = s >> 3, dg = s & 7;
        union { ushort_t h[8]; uint4 u; } p;
        p.u = *(const uint4*)(src + (size_t)(nBase + n) * 512 + dBase + dg * 8);
#pragma unroll
        for (int j = 0; j < 8; ++j) lds[n][dg * 8 + j] = p.h[j];
    }
    __syncthreads();
#pragma unroll
    for (int i = 0; i < 2; ++i) {
        int s = i * 256 + t;
        int d = s >> 3, ng = s & 7;
        union { ushort_t h[8]; uint4 u; } p;
#pragma unroll
        for (int j = 0; j < 8; ++j) p.h[j] = lds[ng * 8 + j][d];
        *(uint4*)(dst + (size_t)(dBase + d) * 2048 + nBase + ng * 8) = p.u;
    }
}

// =====================================================================
__global__ __launch_bounds__(256)
void cvt_bf16(const float* __restrict__ src, ushort_t* __restrict__ dst, int n4)
{
    int i = blockIdx.x * 256 + threadIdx.x;
    if (i >= n4) return;
    float4 v = ((const float4*)src)[i];
    union { ushort_t h[4]; uint2 u; } p;
    p.h[0] = f2bf(v.x); p.h[1] = f2bf(v.y); p.h[2] = f2bf(v.z); p.h[3] = f2bf(v.w);
    ((uint2*)dst)[i] = p.u;
}

__global__ __launch_bounds__(256)
void pack_bias(const float* __restrict__ q, const float* __restrict__ k,
               const float* __restrict__ v, float* __restrict__ dst)
{
    int i = blockIdx.x * 256 + threadIdx.x;
    if (i < 512) dst[i] = q[i];
    else if (i < 1024) dst[i] = k[i - 512];
    else if (i < 1536) dst[i] = v[i - 1024];
}

__global__ __launch_bounds__(256)
void zero_f32(float* __restrict__ p, int n)
{
    int i = blockIdx.x * 256 + threadIdx.x;
    if (i < n) p[i] = 0.f;
}

// =====================================================================
// attn = E/rowsum + intensity, bf16 in-place over E.
// Flat grid-stride streaming (no per-row reduce; rowsum precomputed by QK).
// =====================================================================
__global__ __launch_bounds__(256)
void norm_flat(ushort_t* __restrict__ E, const float* __restrict__ rowsum,
               const float* __restrict__ inten)
{
    const int nG = 4194304;                 // 33.5M bf16 / 8 per granule
    for (int g = blockIdx.x * 256 + threadIdx.x; g < nG; g += gridDim.x * 256) {
        const size_t e0 = (size_t)g * 8;
        const float iv = 1.0f / rowsum[e0 >> 11];   // row = e0/2048
        union { ushort_t h[8]; uint4 u; } p;
        p.u = *(const uint4*)(E + e0);
        float4 i0 = *(const float4*)(inten + e0);
        float4 i1 = *(const float4*)(inten + e0 + 4);
        p.h[0] = f2bf(bf2f(p.h[0]) * iv + i0.x);
        p.h[1] = f2bf(bf2f(p.h[1]) * iv + i0.y);
        p.h[2] = f2bf(bf2f(p.h[2]) * iv + i0.z);
        p.h[3] = f2bf(bf2f(p.h[3]) * iv + i0.w);
        p.h[4] = f2bf(bf2f(p.h[4]) * iv + i1.x);
        p.h[5] = f2bf(bf2f(p.h[5]) * iv + i1.y);
        p.h[6] = f2bf(bf2f(p.h[6]) * iv + i1.z);
        p.h[7] = f2bf(bf2f(p.h[7]) * iv + i1.w);
        *(uint4*)(E + e0) = p.u;
    }
}

// =====================================================================
extern "C" void kernel_launch(void* const* d_in, const int* in_sizes, int n_in,
                              void* d_out, int out_size, void* d_ws, size_t ws_size,
                              hipStream_t stream)
{
    const float* X    = (const float*)d_in[0];
    const float* inten= (const float*)d_in[1];
    const float* WQw  = (const float*)d_in[2];
    const float* WQb  = (const float*)d_in[3];
    const float* WKw  = (const float*)d_in[4];
    const float* WKb  = (const float*)d_in[5];
    const float* WVw  = (const float*)d_in[6];
    const float* WVb  = (const float*)d_in[7];
    const float* Wow  = (const float*)d_in[8];
    const float* Wob  = (const float*)d_in[9];
    float* out = (float*)d_out;

    char* ws = (char*)d_ws;
    ushort_t* Vt    = (ushort_t*)(ws + 0);           // 16 MiB
    ushort_t* Wqkv  = (ushort_t*)(ws + 16777216);    // 1536x512 bf16
    ushort_t* Wob2  = (ushort_t*)(ws + 18350080);    // 512x512 bf16
    float*    biasP = (float*)   (ws + 18874368);    // 1536 f32
    float*    rowsum= (float*)   (ws + 18882560);    // 16384 f32
    ushort_t* QKV   = (ushort_t*)(ws + 19922944);    // Q|K|V row-major, 3x16 MiB
    ushort_t* out1  = (ushort_t*)(ws + 70254592);    // 16 MiB
    ushort_t* Sbf   = (ushort_t*)(ws + 87031808);    // E bf16, 64 MiB
    ushort_t* Xb    = (ushort_t*)(ws + 154140672);   // 16 MiB
    ushort_t* Qb  = QKV;
    ushort_t* Kb  = QKV + 8388608;
    ushort_t* Vrm = QKV + 16777216;

    const float scale = 0.044194173824159216f;       // 1/sqrt(512)

    cvt_bf16<<<dim3(8192), dim3(256), 0, stream>>>(X,   Xb, 2097152);
    cvt_bf16<<<dim3(256),  dim3(256), 0, stream>>>(WQw, Wqkv,          65536);
    cvt_bf16<<<dim3(256),  dim3(256), 0, stream>>>(WKw, Wqkv + 262144, 65536);
    cvt_bf16<<<dim3(256),  dim3(256), 0, stream>>>(WVw, Wqkv + 524288, 65536);
    cvt_bf16<<<dim3(256),  dim3(256), 0, stream>>>(Wow, Wob2,          65536);
    pack_bias<<<dim3(6), dim3(256), 0, stream>>>(WQb, WKb, WVb, biasP);
    zero_f32<<<dim3(64), dim3(256), 0, stream>>>(rowsum, 16384);

    // fused QKV projection: [16384,512] @ [1536,512]^T -> Q|K|V row-major
    gemm_nt<4, 128, 32><<<dim3(12, 128, 1), dim3(256), 0, stream>>>(
        Xb, Wqkv, QKV, biasP, 512, 512, 512, 0, 1.f, 0, 0, 0, nullptr);

    // Vt[b][d][n] = V[b][n][d]
    transpose_v<<<dim3(32, 8, 8), dim3(256), 0, stream>>>(Vrm, Vt);

    // E = exp(scale * Q K^T) bf16 + f32 atomic row sums
    gemm_nt<5, 128, 32><<<dim3(16, 16, 8), dim3(256), 0, stream>>>(
        Qb, Kb, Sbf, nullptr, 512, 512, 512, 2048, scale,
        2048LL * 512, 2048LL * 512, 2048LL * 2048, rowsum);

    // attn = E/rowsum + intensity (bf16, in place, flat streaming)
    norm_flat<<<dim3(2048), dim3(256), 0, stream>>>(Sbf, rowsum, inten);

    // out1 = attn @ Vt^T per batch  [2048,512] bf16
    gemm_nt<0, 64, 32><<<dim3(8, 16, 8), dim3(256), 0, stream>>>(
        Sbf, Vt, out1, nullptr, 2048, 2048, 2048, 512, 1.f,
        2048LL * 2048, 512LL * 2048, 2048LL * 512, nullptr);

    // out = out1 @ Wo^T + bo  [16384,512] f32
    gemm_nt<3, 64, 32><<<dim3(8, 128, 1), dim3(256), 0, stream>>>(
        out1, Wob2, out, Wob, 512, 512, 512, 512, 1.f, 0, 0, 0, nullptr);
}

// Round 11
// 256.962 us; speedup vs baseline: 1.2639x; 1.0340x over previous
//
#include <hip/hip_runtime.h>
#include <stdint.h>

typedef unsigned short ushort_t;
typedef __attribute__((__ext_vector_type__(8))) __bf16 bf16x8;
typedef __attribute__((__ext_vector_type__(4))) float f32x4;

__device__ inline ushort_t f2bf(float f) {
    unsigned int u = __float_as_uint(f);
    u = u + 0x7FFFu + ((u >> 16) & 1u);
    return (ushort_t)(u >> 16);
}
__device__ inline float bf2f(ushort_t h) {
    return __uint_as_float(((unsigned int)h) << 16);
}

#define GLOAD16(gp, lp) __builtin_amdgcn_global_load_lds( \
    (__attribute__((address_space(1))) void*)(gp),        \
    (__attribute__((address_space(3))) void*)(lp), 16, 0, 0)

// =====================================================================
// NT GEMM: C[M,N] = A[M,K] * B[N,K]^T  (A,B bf16-as-ushort)
// BM=128, BN in {128,64}, BK=32. 256 thr = 4 waves (2x2),
// wave tile 64 x (BN/2). MFMA 16x16x32 bf16.
// T3 minimum-2-phase loop (guide §5.5, m230/m248-verified pattern):
//   stage(0,buf0); bar;
//   loop{ stage(it+1,buf1); mfma(buf0); bar;
//         [stage(it+2,buf0);] mfma(buf1); bar; }
// ALL LDS addresses static (4 fixed buffer symbols, manual unroll-by-2;
// NT even for every K used here). No runtime-indexed LDS (r7/r8 lesson).
// XCD-chunked block swizzle (grids multiples of 8).
// MODE 0: C bf16 (+opt bias) | MODE 3: C f32 + bias
// MODE 4: QKV split epilogue (3 row-major [16384,512] outputs)
// MODE 5: C = exp(v*scale) bf16 + f32 atomic row sums
// =====================================================================
template<int MODE, int BN, int BK>
__global__ __launch_bounds__(256)
void gemm_nt(const ushort_t* __restrict__ A, const ushort_t* __restrict__ B,
             void* __restrict__ Cv, const float* __restrict__ bias,
             int K, int lda, int ldb, int ldc, float scale,
             long long sA, long long sB, long long sC,
             float* __restrict__ rsum)
{
    constexpr int WN  = BN / 2;
    constexpr int NR  = WN / 16;
    constexpr int GPR = BK / 8;
    constexpr int AG  = 128 * GPR;
    constexpr int BG  = BN * GPR;
    constexpr int ABYTES = 128 * BK * 2;
    constexpr int BBYTES = BN * BK * 2;
    __shared__ __align__(16) char lds[2 * (ABYTES + BBYTES)];
    char* const ldsA0 = lds;
    char* const ldsB0 = lds + ABYTES;
    char* const ldsA1 = lds + ABYTES + BBYTES;
    char* const ldsB1 = lds + 2 * ABYTES + BBYTES;

    const int t = threadIdx.x;

    // ---- XCD-chunked swizzle ----
    const int gx = gridDim.x, gy = gridDim.y;
    const int nwg = gx * gy * gridDim.z;
    int h = (blockIdx.z * gy + blockIdx.y) * gx + blockIdx.x;
    int logical = (h & 7) * (nwg >> 3) + (h >> 3);
    const int bx = logical % gx;
    const int tmp = logical / gx;
    const int by = tmp % gy;
    const int z  = tmp / gy;

    A += (size_t)z * (size_t)sA;
    B += (size_t)z * (size_t)sB;

    const int rowBase = by * 128;
    const int colBase = bx * BN;

    const int w    = t >> 6;
    const int lane = t & 63;
    const int wr = w >> 1, wc = w & 1;
    const int lr = lane & 15, lg = lane >> 4;

    f32x4 acc[4][NR];
#pragma unroll
    for (int i = 0; i < 4; ++i)
#pragma unroll
        for (int j = 0; j < NR; ++j)
            acc[i][j] = (f32x4){0.f, 0.f, 0.f, 0.f};

    auto stage = [&](int kt, char* dA, char* dB) {
#pragma unroll
        for (int i = 0; i < AG / 256; ++i) {
            const int L = i * 256 + t;
            const int row = L / GPR, g = L % GPR;
            GLOAD16(A + (size_t)(rowBase + row) * (size_t)lda + (kt + g * 8),
                    dA + L * 16);
        }
#pragma unroll
        for (int i = 0; i < BG / 256; ++i) {
            const int L = i * 256 + t;
            const int row = L / GPR, g = L % GPR;
            GLOAD16(B + (size_t)(colBase + row) * (size_t)ldb + (kt + g * 8),
                    dB + L * 16);
        }
    };
    auto mfma_phase = [&](const char* la, const char* lb) {
        const bf16x8* A8 = (const bf16x8*)la;
        const bf16x8* B8 = (const bf16x8*)lb;
#pragma unroll
        for (int kk = 0; kk < BK / 32; ++kk) {
            bf16x8 af[4], bq[NR];
#pragma unroll
            for (int mi = 0; mi < 4; ++mi)
                af[mi] = A8[(wr * 64 + mi * 16 + lr) * GPR + kk * 4 + lg];
#pragma unroll
            for (int ni = 0; ni < NR; ++ni)
                bq[ni] = B8[(wc * WN + ni * 16 + lr) * GPR + kk * 4 + lg];
#pragma unroll
            for (int mi = 0; mi < 4; ++mi)
#pragma unroll
                for (int ni = 0; ni < NR; ++ni)
                    acc[mi][ni] = __builtin_amdgcn_mfma_f32_16x16x32_bf16(
                        af[mi], bq[ni], acc[mi][ni], 0, 0, 0);
        }
    };

    const int NT = K / BK;               // even for all K used (16 or 64)
    stage(0, ldsA0, ldsB0);
    __syncthreads();
    for (int it = 0; it < NT; it += 2) {
        stage((it + 1) * BK, ldsA1, ldsB1);   // next tile in flight
        mfma_phase(ldsA0, ldsB0);             // covers part of the drain
        __syncthreads();
        if (it + 2 < NT) stage((it + 2) * BK, ldsA0, ldsB0);
        mfma_phase(ldsA1, ldsB1);
        __syncthreads();
    }

    // ---- epilogue ----
    float rs[4][4];
    if (MODE == 5) {
#pragma unroll
        for (int mi = 0; mi < 4; ++mi)
#pragma unroll
            for (int r = 0; r < 4; ++r) rs[mi][r] = 0.f;
    }

#pragma unroll
    for (int mi = 0; mi < 4; ++mi) {
#pragma unroll
        for (int ni = 0; ni < NR; ++ni) {
#pragma unroll
            for (int r = 0; r < 4; ++r) {
                const int grow = rowBase + wr * 64 + mi * 16 + lg * 4 + r;
                const int gcol = colBase + wc * WN + ni * 16 + lr;
                float v = acc[mi][ni][r] * scale;
                if (MODE == 0) {
                    if (bias) v += bias[gcol];
                    ushort_t* C = (ushort_t*)Cv + (size_t)z * (size_t)sC;
                    C[(size_t)grow * (size_t)ldc + gcol] = f2bf(v);
                } else if (MODE == 3) {
                    float* C = (float*)Cv;
                    C[(size_t)grow * (size_t)ldc + gcol] = v + bias[gcol];
                } else if (MODE == 4) {
                    v += bias[gcol];
                    const int seg = gcol >> 9, c = gcol & 511;
                    ushort_t* C = (ushort_t*)Cv;
                    C[(size_t)seg * 8388608 + (size_t)grow * 512 + c] = f2bf(v);
                } else { // MODE 5
                    float e = __expf(v);
                    ushort_t* C = (ushort_t*)Cv + (size_t)z * (size_t)sC;
                    C[(size_t)grow * (size_t)ldc + gcol] = f2bf(e);
                    rs[mi][r] += e;
                }
            }
        }
    }

    if (MODE == 5) {
#pragma unroll
        for (int mi = 0; mi < 4; ++mi) {
#pragma unroll
            for (int r = 0; r < 4; ++r) {
                float s = rs[mi][r];
                s += __shfl_xor(s, 1);
                s += __shfl_xor(s, 2);
                s += __shfl_xor(s, 4);
                s += __shfl_xor(s, 8);
                if (lr == 0) {
                    const int grow = rowBase + wr * 64 + mi * 16 + lg * 4 + r;
                    atomicAdd(&rsum[z * 2048 + grow], s);
                }
            }
        }
    }
}

// =====================================================================
// V [8][2048][512] -> Vt [8][512][2048]
// =====================================================================
__global__ __launch_bounds__(256)
void transpose_v(const ushort_t* __restrict__ V, ushort_t* __restrict__ Vt)
{
    __shared__ ushort_t lds[64][68];
    const int t = threadIdx.x;
    const int nBase = blockIdx.x * 64;
    const int dBase = blockIdx.y * 64;
    const size_t b = blockIdx.z;
    const ushort_t* src = V + b * 1048576;
    ushort_t* dst = Vt + b * 1048576;
#pragma unroll
    for (int i = 0; i < 2; ++i) {
        int s = i * 256 + t;
        int n = s >> 3, dg = s & 7;
        union { ushort_t h[8]; uint4 u; } p;
        p.u = *(const uint4*)(src + (size_t)(nBase + n) * 512 + dBase + dg * 8);
#pragma unroll
        for (int j = 0; j < 8; ++j) lds[n][dg * 8 + j] = p.h[j];
    }
    __syncthreads();
#pragma unroll
    for (int i = 0; i < 2; ++i) {
        int s = i * 256 + t;
        int d = s >> 3, ng = s & 7;
        union { ushort_t h[8]; uint4 u; } p;
#pragma unroll
        for (int j = 0; j < 8; ++j) p.h[j] = lds[ng * 8 + j][d];
        *(uint4*)(dst + (size_t)(dBase + d) * 2048 + nBase + ng * 8) = p.u;
    }
}

// =====================================================================
__global__ __launch_bounds__(256)
void cvt_bf16(const float* __restrict__ src, ushort_t* __restrict__ dst, int n4)
{
    int i = blockIdx.x * 256 + threadIdx.x;
    if (i >= n4) return;
    float4 v = ((const float4*)src)[i];
    union { ushort_t h[4]; uint2 u; } p;
    p.h[0] = f2bf(v.x); p.h[1] = f2bf(v.y); p.h[2] = f2bf(v.z); p.h[3] = f2bf(v.w);
    ((uint2*)dst)[i] = p.u;
}

__global__ __launch_bounds__(256)
void pack_bias(const float* __restrict__ q, const float* __restrict__ k,
               const float* __restrict__ v, float* __restrict__ dst)
{
    int i = blockIdx.x * 256 + threadIdx.x;
    if (i < 512) dst[i] = q[i];
    else if (i < 1024) dst[i] = k[i - 512];
    else if (i < 1536) dst[i] = v[i - 1024];
}

__global__ __launch_bounds__(256)
void zero_f32(float* __restrict__ p, int n)
{
    int i = blockIdx.x * 256 + threadIdx.x;
    if (i < n) p[i] = 0.f;
}

// =====================================================================
// attn = E/rowsum + intensity, bf16 in-place over E (flat streaming).
// =====================================================================
__global__ __launch_bounds__(256)
void norm_flat(ushort_t* __restrict__ E, const float* __restrict__ rowsum,
               const float* __restrict__ inten)
{
    const int nG = 4194304;                 // 33.5M bf16 / 8 per granule
    for (int g = blockIdx.x * 256 + threadIdx.x; g < nG; g += gridDim.x * 256) {
        const size_t e0 = (size_t)g * 8;
        const float iv = 1.0f / rowsum[e0 >> 11];   // row = e0/2048
        union { ushort_t h[8]; uint4 u; } p;
        p.u = *(const uint4*)(E + e0);
        float4 i0 = *(const float4*)(inten + e0);
        float4 i1 = *(const float4*)(inten + e0 + 4);
        p.h[0] = f2bf(bf2f(p.h[0]) * iv + i0.x);
        p.h[1] = f2bf(bf2f(p.h[1]) * iv + i0.y);
        p.h[2] = f2bf(bf2f(p.h[2]) * iv + i0.z);
        p.h[3] = f2bf(bf2f(p.h[3]) * iv + i0.w);
        p.h[4] = f2bf(bf2f(p.h[4]) * iv + i1.x);
        p.h[5] = f2bf(bf2f(p.h[5]) * iv + i1.y);
        p.h[6] = f2bf(bf2f(p.h[6]) * iv + i1.z);
        p.h[7] = f2bf(bf2f(p.h[7]) * iv + i1.w);
        *(uint4*)(E + e0) = p.u;
    }
}

// =====================================================================
extern "C" void kernel_launch(void* const* d_in, const int* in_sizes, int n_in,
                              void* d_out, int out_size, void* d_ws, size_t ws_size,
                              hipStream_t stream)
{
    const float* X    = (const float*)d_in[0];
    const float* inten= (const float*)d_in[1];
    const float* WQw  = (const float*)d_in[2];
    const float* WQb  = (const float*)d_in[3];
    const float* WKw  = (const float*)d_in[4];
    const float* WKb  = (const float*)d_in[5];
    const float* WVw  = (const float*)d_in[6];
    const float* WVb  = (const float*)d_in[7];
    const float* Wow  = (const float*)d_in[8];
    const float* Wob  = (const float*)d_in[9];
    float* out = (float*)d_out;

    char* ws = (char*)d_ws;
    ushort_t* Vt    = (ushort_t*)(ws + 0);           // 16 MiB
    ushort_t* Wqkv  = (ushort_t*)(ws + 16777216);    // 1536x512 bf16
    ushort_t* Wob2  = (ushort_t*)(ws + 18350080);    // 512x512 bf16
    float*    biasP = (float*)   (ws + 18874368);    // 1536 f32
    float*    rowsum= (float*)   (ws + 18882560);    // 16384 f32
    ushort_t* QKV   = (ushort_t*)(ws + 19922944);    // Q|K|V row-major, 3x16 MiB
    ushort_t* out1  = (ushort_t*)(ws + 70254592);    // 16 MiB
    ushort_t* Sbf   = (ushort_t*)(ws + 87031808);    // E bf16, 64 MiB
    ushort_t* Xb    = (ushort_t*)(ws + 154140672);   // 16 MiB
    ushort_t* Qb  = QKV;
    ushort_t* Kb  = QKV + 8388608;
    ushort_t* Vrm = QKV + 16777216;

    const float scale = 0.044194173824159216f;       // 1/sqrt(512)

    cvt_bf16<<<dim3(8192), dim3(256), 0, stream>>>(X,   Xb, 2097152);
    cvt_bf16<<<dim3(256),  dim3(256), 0, stream>>>(WQw, Wqkv,          65536);
    cvt_bf16<<<dim3(256),  dim3(256), 0, stream>>>(WKw, Wqkv + 262144, 65536);
    cvt_bf16<<<dim3(256),  dim3(256), 0, stream>>>(WVw, Wqkv + 524288, 65536);
    cvt_bf16<<<dim3(256),  dim3(256), 0, stream>>>(Wow, Wob2,          65536);
    pack_bias<<<dim3(6), dim3(256), 0, stream>>>(WQb, WKb, WVb, biasP);
    zero_f32<<<dim3(64), dim3(256), 0, stream>>>(rowsum, 16384);

    // fused QKV projection: [16384,512] @ [1536,512]^T -> Q|K|V row-major
    gemm_nt<4, 128, 32><<<dim3(12, 128, 1), dim3(256), 0, stream>>>(
        Xb, Wqkv, QKV, biasP, 512, 512, 512, 0, 1.f, 0, 0, 0, nullptr);

    // Vt[b][d][n] = V[b][n][d]
    transpose_v<<<dim3(32, 8, 8), dim3(256), 0, stream>>>(Vrm, Vt);

    // E = exp(scale * Q K^T) bf16 + f32 atomic row sums
    gemm_nt<5, 128, 32><<<dim3(16, 16, 8), dim3(256), 0, stream>>>(
        Qb, Kb, Sbf, nullptr, 512, 512, 512, 2048, scale,
        2048LL * 512, 2048LL * 512, 2048LL * 2048, rowsum);

    // attn = E/rowsum + intensity (bf16, in place, flat streaming)
    norm_flat<<<dim3(2048), dim3(256), 0, stream>>>(Sbf, rowsum, inten);

    // out1 = attn @ Vt^T per batch  [2048,512] bf16
    gemm_nt<0, 64, 32><<<dim3(8, 16, 8), dim3(256), 0, stream>>>(
        Sbf, Vt, out1, nullptr, 2048, 2048, 2048, 512, 1.f,
        2048LL * 2048, 512LL * 2048, 2048LL * 512, nullptr);

    // out = out1 @ Wo^T + bo  [16384,512] f32
    gemm_nt<3, 64, 32><<<dim3(8, 128, 1), dim3(256), 0, stream>>>(
        out1, Wob2, out, Wob, 512, 512, 512, 512, 1.f, 0, 0, 0, nullptr);
}

// Round 12
// 242.120 us; speedup vs baseline: 1.3414x; 1.0613x over previous
//
#include <hip/hip_runtime.h>
#include <stdint.h>

typedef unsigned short ushort_t;
typedef __attribute__((__ext_vector_type__(8))) __bf16 bf16x8;
typedef __attribute__((__ext_vector_type__(4))) float f32x4;

__device__ inline ushort_t f2bf(float f) {
    unsigned int u = __float_as_uint(f);
    u = u + 0x7FFFu + ((u >> 16) & 1u);
    return (ushort_t)(u >> 16);
}
__device__ inline float bf2f(ushort_t h) {
    return __uint_as_float(((unsigned int)h) << 16);
}

#define GLOAD16(gp, lp) __builtin_amdgcn_global_load_lds( \
    (__attribute__((address_space(1))) void*)(gp),        \
    (__attribute__((address_space(3))) void*)(lp), 16, 0, 0)

// =====================================================================
// NT GEMM: C[M,N] = A[M,K] * B[N,K]^T  (A,B bf16-as-ushort)
// BM=128, BN in {128,64}, BK=32. 256 thr = 4 waves (2x2),
// wave tile 64 x (BN/2). MFMA 16x16x32 bf16.
// T3 minimum-2-phase loop (r11-proven): static 4-buffer dbuf, unroll-by-2.
// XCD-chunked block swizzle (grids multiples of 8).
// MODE 0: C bf16 (+opt bias) | MODE 3: C f32 + bias
// MODE 4: QKV split epilogue (3 row-major [16384,512] outputs)
// MODE 5: C = exp(v*scale) bf16 (NO atomics — r4/r11 A/B: atomics cost ~15us)
// =====================================================================
template<int MODE, int BN, int BK>
__global__ __launch_bounds__(256)
void gemm_nt(const ushort_t* __restrict__ A, const ushort_t* __restrict__ B,
             void* __restrict__ Cv, const float* __restrict__ bias,
             int K, int lda, int ldb, int ldc, float scale,
             long long sA, long long sB, long long sC)
{
    constexpr int WN  = BN / 2;
    constexpr int NR  = WN / 16;
    constexpr int GPR = BK / 8;
    constexpr int AG  = 128 * GPR;
    constexpr int BG  = BN * GPR;
    constexpr int ABYTES = 128 * BK * 2;
    constexpr int BBYTES = BN * BK * 2;
    __shared__ __align__(16) char lds[2 * (ABYTES + BBYTES)];
    char* const ldsA0 = lds;
    char* const ldsB0 = lds + ABYTES;
    char* const ldsA1 = lds + ABYTES + BBYTES;
    char* const ldsB1 = lds + 2 * ABYTES + BBYTES;

    const int t = threadIdx.x;

    // ---- XCD-chunked swizzle ----
    const int gx = gridDim.x, gy = gridDim.y;
    const int nwg = gx * gy * gridDim.z;
    int h = (blockIdx.z * gy + blockIdx.y) * gx + blockIdx.x;
    int logical = (h & 7) * (nwg >> 3) + (h >> 3);
    const int bx = logical % gx;
    const int tmp = logical / gx;
    const int by = tmp % gy;
    const int z  = tmp / gy;

    A += (size_t)z * (size_t)sA;
    B += (size_t)z * (size_t)sB;

    const int rowBase = by * 128;
    const int colBase = bx * BN;

    const int w    = t >> 6;
    const int lane = t & 63;
    const int wr = w >> 1, wc = w & 1;
    const int lr = lane & 15, lg = lane >> 4;

    f32x4 acc[4][NR];
#pragma unroll
    for (int i = 0; i < 4; ++i)
#pragma unroll
        for (int j = 0; j < NR; ++j)
            acc[i][j] = (f32x4){0.f, 0.f, 0.f, 0.f};

    auto stage = [&](int kt, char* dA, char* dB) {
#pragma unroll
        for (int i = 0; i < AG / 256; ++i) {
            const int L = i * 256 + t;
            const int row = L / GPR, g = L % GPR;
            GLOAD16(A + (size_t)(rowBase + row) * (size_t)lda + (kt + g * 8),
                    dA + L * 16);
        }
#pragma unroll
        for (int i = 0; i < BG / 256; ++i) {
            const int L = i * 256 + t;
            const int row = L / GPR, g = L % GPR;
            GLOAD16(B + (size_t)(colBase + row) * (size_t)ldb + (kt + g * 8),
                    dB + L * 16);
        }
    };
    auto mfma_phase = [&](const char* la, const char* lb) {
        const bf16x8* A8 = (const bf16x8*)la;
        const bf16x8* B8 = (const bf16x8*)lb;
#pragma unroll
        for (int kk = 0; kk < BK / 32; ++kk) {
            bf16x8 af[4], bq[NR];
#pragma unroll
            for (int mi = 0; mi < 4; ++mi)
                af[mi] = A8[(wr * 64 + mi * 16 + lr) * GPR + kk * 4 + lg];
#pragma unroll
            for (int ni = 0; ni < NR; ++ni)
                bq[ni] = B8[(wc * WN + ni * 16 + lr) * GPR + kk * 4 + lg];
#pragma unroll
            for (int mi = 0; mi < 4; ++mi)
#pragma unroll
                for (int ni = 0; ni < NR; ++ni)
                    acc[mi][ni] = __builtin_amdgcn_mfma_f32_16x16x32_bf16(
                        af[mi], bq[ni], acc[mi][ni], 0, 0, 0);
        }
    };

    const int NT = K / BK;               // even for all K used (16 or 64)
    stage(0, ldsA0, ldsB0);
    __syncthreads();
    for (int it = 0; it < NT; it += 2) {
        stage((it + 1) * BK, ldsA1, ldsB1);   // next tile in flight
        mfma_phase(ldsA0, ldsB0);             // covers part of the drain
        __syncthreads();
        if (it + 2 < NT) stage((it + 2) * BK, ldsA0, ldsB0);
        mfma_phase(ldsA1, ldsB1);
        __syncthreads();
    }

    // ---- epilogue ----
#pragma unroll
    for (int mi = 0; mi < 4; ++mi) {
#pragma unroll
        for (int ni = 0; ni < NR; ++ni) {
#pragma unroll
            for (int r = 0; r < 4; ++r) {
                const int grow = rowBase + wr * 64 + mi * 16 + lg * 4 + r;
                const int gcol = colBase + wc * WN + ni * 16 + lr;
                float v = acc[mi][ni][r] * scale;
                if (MODE == 0) {
                    if (bias) v += bias[gcol];
                    ushort_t* C = (ushort_t*)Cv + (size_t)z * (size_t)sC;
                    C[(size_t)grow * (size_t)ldc + gcol] = f2bf(v);
                } else if (MODE == 3) {
                    float* C = (float*)Cv;
                    C[(size_t)grow * (size_t)ldc + gcol] = v + bias[gcol];
                } else if (MODE == 4) {
                    v += bias[gcol];
                    const int seg = gcol >> 9, c = gcol & 511;
                    ushort_t* C = (ushort_t*)Cv;
                    C[(size_t)seg * 8388608 + (size_t)grow * 512 + c] = f2bf(v);
                } else { // MODE 5: E = exp(score), plain store
                    ushort_t* C = (ushort_t*)Cv + (size_t)z * (size_t)sC;
                    C[(size_t)grow * (size_t)ldc + gcol] = f2bf(__expf(v));
                }
            }
        }
    }
}

// =====================================================================
// V [8][2048][512] -> Vt [8][512][2048]
// =====================================================================
__global__ __launch_bounds__(256)
void transpose_v(const ushort_t* __restrict__ V, ushort_t* __restrict__ Vt)
{
    __shared__ ushort_t lds[64][68];
    const int t = threadIdx.x;
    const int nBase = blockIdx.x * 64;
    const int dBase = blockIdx.y * 64;
    const size_t b = blockIdx.z;
    const ushort_t* src = V + b * 1048576;
    ushort_t* dst = Vt + b * 1048576;
#pragma unroll
    for (int i = 0; i < 2; ++i) {
        int s = i * 256 + t;
        int n = s >> 3, dg = s & 7;
        union { ushort_t h[8]; uint4 u; } p;
        p.u = *(const uint4*)(src + (size_t)(nBase + n) * 512 + dBase + dg * 8);
#pragma unroll
        for (int j = 0; j < 8; ++j) lds[n][dg * 8 + j] = p.h[j];
    }
    __syncthreads();
#pragma unroll
    for (int i = 0; i < 2; ++i) {
        int s = i * 256 + t;
        int d = s >> 3, ng = s & 7;
        union { ushort_t h[8]; uint4 u; } p;
#pragma unroll
        for (int j = 0; j < 8; ++j) p.h[j] = lds[ng * 8 + j][d];
        *(uint4*)(dst + (size_t)(dBase + d) * 2048 + nBase + ng * 8) = p.u;
    }
}

// =====================================================================
__global__ __launch_bounds__(256)
void cvt_bf16(const float* __restrict__ src, ushort_t* __restrict__ dst, int n4)
{
    int i = blockIdx.x * 256 + threadIdx.x;
    if (i >= n4) return;
    float4 v = ((const float4*)src)[i];
    union { ushort_t h[4]; uint2 u; } p;
    p.h[0] = f2bf(v.x); p.h[1] = f2bf(v.y); p.h[2] = f2bf(v.z); p.h[3] = f2bf(v.w);
    ((uint2*)dst)[i] = p.u;
}

__global__ __launch_bounds__(256)
void pack_bias(const float* __restrict__ q, const float* __restrict__ k,
               const float* __restrict__ v, float* __restrict__ dst)
{
    int i = blockIdx.x * 256 + threadIdx.x;
    if (i < 512) dst[i] = q[i];
    else if (i < 1024) dst[i] = k[i - 512];
    else if (i < 1536) dst[i] = v[i - 1024];
}

// =====================================================================
// attn = E/rowsum + intensity, bf16 in-place over E. One block per row;
// the block computes the row sum itself (r4-proven, no atomics).
// =====================================================================
__global__ __launch_bounds__(256)
void norm_add(ushort_t* __restrict__ E, const float* __restrict__ inten)
{
    const int R = blockIdx.x;            // 0..16383
    const int t = threadIdx.x;
    const int w = t >> 6, lane = t & 63;
    ushort_t* erow = E + (size_t)R * 2048;
    const float* irow = inten + (size_t)R * 2048;

    union { ushort_t h[8]; uint4 u; } p;
    p.u = *(const uint4*)(erow + t * 8);
    float f[8];
#pragma unroll
    for (int j = 0; j < 8; ++j) f[j] = bf2f(p.h[j]);

    float s = 0.f;
#pragma unroll
    for (int j = 0; j < 8; ++j) s += f[j];
#pragma unroll
    for (int off = 32; off > 0; off >>= 1) s += __shfl_xor(s, off);

    __shared__ float red[4];
    if (lane == 0) red[w] = s;
    __syncthreads();
    const float inv = 1.f / (red[0] + red[1] + red[2] + red[3]);

    float4 i0 = *(const float4*)(irow + t * 8);
    float4 i1 = *(const float4*)(irow + t * 8 + 4);
    float o[8] = { f[0]*inv + i0.x, f[1]*inv + i0.y, f[2]*inv + i0.z, f[3]*inv + i0.w,
                   f[4]*inv + i1.x, f[5]*inv + i1.y, f[6]*inv + i1.z, f[7]*inv + i1.w };
#pragma unroll
    for (int j = 0; j < 8; ++j) p.h[j] = f2bf(o[j]);
    *(uint4*)(erow + t * 8) = p.u;
}

// =====================================================================
extern "C" void kernel_launch(void* const* d_in, const int* in_sizes, int n_in,
                              void* d_out, int out_size, void* d_ws, size_t ws_size,
                              hipStream_t stream)
{
    const float* X    = (const float*)d_in[0];
    const float* inten= (const float*)d_in[1];
    const float* WQw  = (const float*)d_in[2];
    const float* WQb  = (const float*)d_in[3];
    const float* WKw  = (const float*)d_in[4];
    const float* WKb  = (const float*)d_in[5];
    const float* WVw  = (const float*)d_in[6];
    const float* WVb  = (const float*)d_in[7];
    const float* Wow  = (const float*)d_in[8];
    const float* Wob  = (const float*)d_in[9];
    float* out = (float*)d_out;

    char* ws = (char*)d_ws;
    ushort_t* Vt    = (ushort_t*)(ws + 0);           // 16 MiB
    ushort_t* Wqkv  = (ushort_t*)(ws + 16777216);    // 1536x512 bf16
    ushort_t* Wob2  = (ushort_t*)(ws + 18350080);    // 512x512 bf16
    float*    biasP = (float*)   (ws + 18874368);    // 1536 f32
    ushort_t* QKV   = (ushort_t*)(ws + 19922944);    // Q|K|V row-major, 3x16 MiB
    ushort_t* out1  = (ushort_t*)(ws + 70254592);    // 16 MiB
    ushort_t* Sbf   = (ushort_t*)(ws + 87031808);    // E bf16, 64 MiB
    ushort_t* Xb    = (ushort_t*)(ws + 154140672);   // 16 MiB
    ushort_t* Qb  = QKV;
    ushort_t* Kb  = QKV + 8388608;
    ushort_t* Vrm = QKV + 16777216;

    const float scale = 0.044194173824159216f;       // 1/sqrt(512)

    cvt_bf16<<<dim3(8192), dim3(256), 0, stream>>>(X,   Xb, 2097152);
    cvt_bf16<<<dim3(256),  dim3(256), 0, stream>>>(WQw, Wqkv,          65536);
    cvt_bf16<<<dim3(256),  dim3(256), 0, stream>>>(WKw, Wqkv + 262144, 65536);
    cvt_bf16<<<dim3(256),  dim3(256), 0, stream>>>(WVw, Wqkv + 524288, 65536);
    cvt_bf16<<<dim3(256),  dim3(256), 0, stream>>>(Wow, Wob2,          65536);
    pack_bias<<<dim3(6), dim3(256), 0, stream>>>(WQb, WKb, WVb, biasP);

    // fused QKV projection: [16384,512] @ [1536,512]^T -> Q|K|V row-major
    gemm_nt<4, 128, 32><<<dim3(12, 128, 1), dim3(256), 0, stream>>>(
        Xb, Wqkv, QKV, biasP, 512, 512, 512, 0, 1.f, 0, 0, 0);

    // Vt[b][d][n] = V[b][n][d]
    transpose_v<<<dim3(32, 8, 8), dim3(256), 0, stream>>>(Vrm, Vt);

    // E = exp(scale * Q K^T) bf16, per batch
    gemm_nt<5, 128, 32><<<dim3(16, 16, 8), dim3(256), 0, stream>>>(
        Qb, Kb, Sbf, nullptr, 512, 512, 512, 2048, scale,
        2048LL * 512, 2048LL * 512, 2048LL * 2048);

    // attn = E/rowsum + intensity (bf16, in place, self-reducing)
    norm_add<<<dim3(16384), dim3(256), 0, stream>>>(Sbf, inten);

    // out1 = attn @ Vt^T per batch  [2048,512] bf16
    gemm_nt<0, 64, 32><<<dim3(8, 16, 8), dim3(256), 0, stream>>>(
        Sbf, Vt, out1, nullptr, 2048, 2048, 2048, 512, 1.f,
        2048LL * 2048, 512LL * 2048, 2048LL * 512);

    // out = out1 @ Wo^T + bo  [16384,512] f32
    gemm_nt<3, 64, 32><<<dim3(8, 128, 1), dim3(256), 0, stream>>>(
        out1, Wob2, out, Wob, 512, 512, 512, 512, 1.f, 0, 0, 0);
}

// Round 13
// 230.076 us; speedup vs baseline: 1.4116x; 1.0523x over previous
//
#include <hip/hip_runtime.h>
#include <stdint.h>

typedef unsigned short ushort_t;
typedef __attribute__((__ext_vector_type__(8))) __bf16 bf16x8;
typedef __attribute__((__ext_vector_type__(4))) float f32x4;

__device__ inline ushort_t f2bf(float f) {
    unsigned int u = __float_as_uint(f);
    u = u + 0x7FFFu + ((u >> 16) & 1u);
    return (ushort_t)(u >> 16);
}
__device__ inline float bf2f(ushort_t h) {
    return __uint_as_float(((unsigned int)h) << 16);
}

#define GLOAD16(gp, lp) __builtin_amdgcn_global_load_lds( \
    (__attribute__((address_space(1))) void*)(gp),        \
    (__attribute__((address_space(3))) void*)(lp), 16, 0, 0)

// =====================================================================
// NT GEMM: C[M,N] = A[M,K] * B[N,K]^T  (A,B bf16-as-ushort)
// BM=128, BN in {128,64}, BK=32. 256 thr = 4 waves (2x2),
// wave tile 64 x (BN/2). MFMA 16x16x32 bf16.
// T3 minimum-2-phase loop (r11/r12-proven): static 4-buffer dbuf.
// T2 granule swizzle (rule 21: linear LDS dest + inverse-swizzled global
// SOURCE + swizzled READ): LDS slot (row,g) holds global granule
// g ^ ((row>>1)&3); read of fragment lg uses slot lg ^ ((row>>1)&3).
// Spreads the 16 stride-64B rows of a ds_read_b128 over 8 distinct
// byte-mod-128 positions (2 lanes each = conflict-free, m136).
// XCD-chunked block swizzle (grids multiples of 8).
// MODE 0: C bf16 (+opt bias) | MODE 3: C f32 + bias
// MODE 4: QKV split epilogue | MODE 5: C = exp(v*scale) bf16 (no atomics)
// =====================================================================
template<int MODE, int BN, int BK>
__global__ __launch_bounds__(256)
void gemm_nt(const ushort_t* __restrict__ A, const ushort_t* __restrict__ B,
             void* __restrict__ Cv, const float* __restrict__ bias,
             int K, int lda, int ldb, int ldc, float scale,
             long long sA, long long sB, long long sC)
{
    constexpr int WN  = BN / 2;
    constexpr int NR  = WN / 16;
    constexpr int GPR = BK / 8;          // 4 for BK=32
    constexpr int AG  = 128 * GPR;
    constexpr int BG  = BN * GPR;
    constexpr int ABYTES = 128 * BK * 2;
    constexpr int BBYTES = BN * BK * 2;
    __shared__ __align__(16) char lds[2 * (ABYTES + BBYTES)];
    char* const ldsA0 = lds;
    char* const ldsB0 = lds + ABYTES;
    char* const ldsA1 = lds + ABYTES + BBYTES;
    char* const ldsB1 = lds + 2 * ABYTES + BBYTES;

    const int t = threadIdx.x;

    // ---- XCD-chunked swizzle ----
    const int gx = gridDim.x, gy = gridDim.y;
    const int nwg = gx * gy * gridDim.z;
    int h = (blockIdx.z * gy + blockIdx.y) * gx + blockIdx.x;
    int logical = (h & 7) * (nwg >> 3) + (h >> 3);
    const int bx = logical % gx;
    const int tmp = logical / gx;
    const int by = tmp % gy;
    const int z  = tmp / gy;

    A += (size_t)z * (size_t)sA;
    B += (size_t)z * (size_t)sB;

    const int rowBase = by * 128;
    const int colBase = bx * BN;

    const int w    = t >> 6;
    const int lane = t & 63;
    const int wr = w >> 1, wc = w & 1;
    const int lr = lane & 15, lg = lane >> 4;

    f32x4 acc[4][NR];
#pragma unroll
    for (int i = 0; i < 4; ++i)
#pragma unroll
        for (int j = 0; j < NR; ++j)
            acc[i][j] = (f32x4){0.f, 0.f, 0.f, 0.f};

    auto stage = [&](int kt, char* dA, char* dB) {
#pragma unroll
        for (int i = 0; i < AG / 256; ++i) {
            const int L = i * 256 + t;
            const int row = L / GPR, g = L % GPR;
            const int gs = g ^ ((row >> 1) & 3);   // inverse-swizzled source
            GLOAD16(A + (size_t)(rowBase + row) * (size_t)lda + (kt + gs * 8),
                    dA + L * 16);
        }
#pragma unroll
        for (int i = 0; i < BG / 256; ++i) {
            const int L = i * 256 + t;
            const int row = L / GPR, g = L % GPR;
            const int gs = g ^ ((row >> 1) & 3);
            GLOAD16(B + (size_t)(colBase + row) * (size_t)ldb + (kt + gs * 8),
                    dB + L * 16);
        }
    };
    auto mfma_phase = [&](const char* la, const char* lb) {
        const bf16x8* A8 = (const bf16x8*)la;
        const bf16x8* B8 = (const bf16x8*)lb;
#pragma unroll
        for (int kk = 0; kk < BK / 32; ++kk) {
            bf16x8 af[4], bq[NR];
#pragma unroll
            for (int mi = 0; mi < 4; ++mi) {
                const int ar = wr * 64 + mi * 16 + lr;
                af[mi] = A8[ar * GPR + ((kk * 4 + lg) ^ ((ar >> 1) & 3))];
            }
#pragma unroll
            for (int ni = 0; ni < NR; ++ni) {
                const int br = wc * WN + ni * 16 + lr;
                bq[ni] = B8[br * GPR + ((kk * 4 + lg) ^ ((br >> 1) & 3))];
            }
#pragma unroll
            for (int mi = 0; mi < 4; ++mi)
#pragma unroll
                for (int ni = 0; ni < NR; ++ni)
                    acc[mi][ni] = __builtin_amdgcn_mfma_f32_16x16x32_bf16(
                        af[mi], bq[ni], acc[mi][ni], 0, 0, 0);
        }
    };

    const int NT = K / BK;               // even for all K used (16 or 64)
    stage(0, ldsA0, ldsB0);
    __syncthreads();
    for (int it = 0; it < NT; it += 2) {
        stage((it + 1) * BK, ldsA1, ldsB1);   // next tile in flight
        mfma_phase(ldsA0, ldsB0);             // covers part of the drain
        __syncthreads();
        if (it + 2 < NT) stage((it + 2) * BK, ldsA0, ldsB0);
        mfma_phase(ldsA1, ldsB1);
        __syncthreads();
    }

    // ---- epilogue ----
#pragma unroll
    for (int mi = 0; mi < 4; ++mi) {
#pragma unroll
        for (int ni = 0; ni < NR; ++ni) {
#pragma unroll
            for (int r = 0; r < 4; ++r) {
                const int grow = rowBase + wr * 64 + mi * 16 + lg * 4 + r;
                const int gcol = colBase + wc * WN + ni * 16 + lr;
                float v = acc[mi][ni][r] * scale;
                if (MODE == 0) {
                    if (bias) v += bias[gcol];
                    ushort_t* C = (ushort_t*)Cv + (size_t)z * (size_t)sC;
                    C[(size_t)grow * (size_t)ldc + gcol] = f2bf(v);
                } else if (MODE == 3) {
                    float* C = (float*)Cv;
                    C[(size_t)grow * (size_t)ldc + gcol] = v + bias[gcol];
                } else if (MODE == 4) {
                    v += bias[gcol];
                    const int seg = gcol >> 9, c = gcol & 511;
                    ushort_t* C = (ushort_t*)Cv;
                    C[(size_t)seg * 8388608 + (size_t)grow * 512 + c] = f2bf(v);
                } else { // MODE 5: E = exp(score), plain store
                    ushort_t* C = (ushort_t*)Cv + (size_t)z * (size_t)sC;
                    C[(size_t)grow * (size_t)ldc + gcol] = f2bf(__expf(v));
                }
            }
        }
    }
}

// =====================================================================
// V [8][2048][512] -> Vt [8][512][2048]
// =====================================================================
__global__ __launch_bounds__(256)
void transpose_v(const ushort_t* __restrict__ V, ushort_t* __restrict__ Vt)
{
    __shared__ ushort_t lds[64][68];
    const int t = threadIdx.x;
    const int nBase = blockIdx.x * 64;
    const int dBase = blockIdx.y * 64;
    const size_t b = blockIdx.z;
    const ushort_t* src = V + b * 1048576;
    ushort_t* dst = Vt + b * 1048576;
#pragma unroll
    for (int i = 0; i < 2; ++i) {
        int s = i * 256 + t;
        int n = s >> 3, dg = s & 7;
        union { ushort_t h[8]; uint4 u; } p;
        p.u = *(const uint4*)(src + (size_t)(nBase + n) * 512 + dBase + dg * 8);
#pragma unroll
        for (int j = 0; j < 8; ++j) lds[n][dg * 8 + j] = p.h[j];
    }
    __syncthreads();
#pragma unroll
    for (int i = 0; i < 2; ++i) {
        int s = i * 256 + t;
        int d = s >> 3, ng = s & 7;
        union { ushort_t h[8]; uint4 u; } p;
#pragma unroll
        for (int j = 0; j < 8; ++j) p.h[j] = lds[ng * 8 + j][d];
        *(uint4*)(dst + (size_t)(dBase + d) * 2048 + nBase + ng * 8) = p.u;
    }
}

// =====================================================================
__global__ __launch_bounds__(256)
void cvt_bf16(const float* __restrict__ src, ushort_t* __restrict__ dst, int n4)
{
    int i = blockIdx.x * 256 + threadIdx.x;
    if (i >= n4) return;
    float4 v = ((const float4*)src)[i];
    union { ushort_t h[4]; uint2 u; } p;
    p.h[0] = f2bf(v.x); p.h[1] = f2bf(v.y); p.h[2] = f2bf(v.z); p.h[3] = f2bf(v.w);
    ((uint2*)dst)[i] = p.u;
}

__global__ __launch_bounds__(256)
void pack_bias(const float* __restrict__ q, const float* __restrict__ k,
               const float* __restrict__ v, float* __restrict__ dst)
{
    int i = blockIdx.x * 256 + threadIdx.x;
    if (i < 512) dst[i] = q[i];
    else if (i < 1024) dst[i] = k[i - 512];
    else if (i < 1536) dst[i] = v[i - 1024];
}

// =====================================================================
// attn = E/rowsum + intensity, bf16 in-place over E. One block per row;
// the block computes the row sum itself (no atomics).
// =====================================================================
__global__ __launch_bounds__(256)
void norm_add(ushort_t* __restrict__ E, const float* __restrict__ inten)
{
    const int R = blockIdx.x;            // 0..16383
    const int t = threadIdx.x;
    const int w = t >> 6, lane = t & 63;
    ushort_t* erow = E + (size_t)R * 2048;
    const float* irow = inten + (size_t)R * 2048;

    union { ushort_t h[8]; uint4 u; } p;
    p.u = *(const uint4*)(erow + t * 8);
    float f[8];
#pragma unroll
    for (int j = 0; j < 8; ++j) f[j] = bf2f(p.h[j]);

    float s = 0.f;
#pragma unroll
    for (int j = 0; j < 8; ++j) s += f[j];
#pragma unroll
    for (int off = 32; off > 0; off >>= 1) s += __shfl_xor(s, off);

    __shared__ float red[4];
    if (lane == 0) red[w] = s;
    __syncthreads();
    const float inv = 1.f / (red[0] + red[1] + red[2] + red[3]);

    float4 i0 = *(const float4*)(irow + t * 8);
    float4 i1 = *(const float4*)(irow + t * 8 + 4);
    float o[8] = { f[0]*inv + i0.x, f[1]*inv + i0.y, f[2]*inv + i0.z, f[3]*inv + i0.w,
                   f[4]*inv + i1.x, f[5]*inv + i1.y, f[6]*inv + i1.z, f[7]*inv + i1.w };
#pragma unroll
    for (int j = 0; j < 8; ++j) p.h[j] = f2bf(o[j]);
    *(uint4*)(erow + t * 8) = p.u;
}

// =====================================================================
extern "C" void kernel_launch(void* const* d_in, const int* in_sizes, int n_in,
                              void* d_out, int out_size, void* d_ws, size_t ws_size,
                              hipStream_t stream)
{
    const float* X    = (const float*)d_in[0];
    const float* inten= (const float*)d_in[1];
    const float* WQw  = (const float*)d_in[2];
    const float* WQb  = (const float*)d_in[3];
    const float* WKw  = (const float*)d_in[4];
    const float* WKb  = (const float*)d_in[5];
    const float* WVw  = (const float*)d_in[6];
    const float* WVb  = (const float*)d_in[7];
    const float* Wow  = (const float*)d_in[8];
    const float* Wob  = (const float*)d_in[9];
    float* out = (float*)d_out;

    char* ws = (char*)d_ws;
    ushort_t* Vt    = (ushort_t*)(ws + 0);           // 16 MiB
    ushort_t* Wqkv  = (ushort_t*)(ws + 16777216);    // 1536x512 bf16
    ushort_t* Wob2  = (ushort_t*)(ws + 18350080);    // 512x512 bf16
    float*    biasP = (float*)   (ws + 18874368);    // 1536 f32
    ushort_t* QKV   = (ushort_t*)(ws + 19922944);    // Q|K|V row-major, 3x16 MiB
    ushort_t* out1  = (ushort_t*)(ws + 70254592);    // 16 MiB
    ushort_t* Sbf   = (ushort_t*)(ws + 87031808);    // E bf16, 64 MiB
    ushort_t* Xb    = (ushort_t*)(ws + 154140672);   // 16 MiB
    ushort_t* Qb  = QKV;
    ushort_t* Kb  = QKV + 8388608;
    ushort_t* Vrm = QKV + 16777216;

    const float scale = 0.044194173824159216f;       // 1/sqrt(512)

    cvt_bf16<<<dim3(8192), dim3(256), 0, stream>>>(X,   Xb, 2097152);
    cvt_bf16<<<dim3(256),  dim3(256), 0, stream>>>(WQw, Wqkv,          65536);
    cvt_bf16<<<dim3(256),  dim3(256), 0, stream>>>(WKw, Wqkv + 262144, 65536);
    cvt_bf16<<<dim3(256),  dim3(256), 0, stream>>>(WVw, Wqkv + 524288, 65536);
    cvt_bf16<<<dim3(256),  dim3(256), 0, stream>>>(Wow, Wob2,          65536);
    pack_bias<<<dim3(6), dim3(256), 0, stream>>>(WQb, WKb, WVb, biasP);

    // fused QKV projection: [16384,512] @ [1536,512]^T -> Q|K|V row-major
    gemm_nt<4, 128, 32><<<dim3(12, 128, 1), dim3(256), 0, stream>>>(
        Xb, Wqkv, QKV, biasP, 512, 512, 512, 0, 1.f, 0, 0, 0);

    // Vt[b][d][n] = V[b][n][d]
    transpose_v<<<dim3(32, 8, 8), dim3(256), 0, stream>>>(Vrm, Vt);

    // E = exp(scale * Q K^T) bf16, per batch
    gemm_nt<5, 128, 32><<<dim3(16, 16, 8), dim3(256), 0, stream>>>(
        Qb, Kb, Sbf, nullptr, 512, 512, 512, 2048, scale,
        2048LL * 512, 2048LL * 512, 2048LL * 2048);

    // attn = E/rowsum + intensity (bf16, in place, self-reducing)
    norm_add<<<dim3(16384), dim3(256), 0, stream>>>(Sbf, inten);

    // out1 = attn @ Vt^T per batch  [2048,512] bf16
    gemm_nt<0, 64, 32><<<dim3(8, 16, 8), dim3(256), 0, stream>>>(
        Sbf, Vt, out1, nullptr, 2048, 2048, 2048, 512, 1.f,
        2048LL * 2048, 512LL * 2048, 2048LL * 512);

    // out = out1 @ Wo^T + bo  [16384,512] f32
    gemm_nt<3, 64, 32><<<dim3(8, 128, 1), dim3(256), 0, stream>>>(
        out1, Wob2, out, Wob, 512, 512, 512, 512, 1.f, 0, 0, 0);
}

// Round 14
// 211.712 us; speedup vs baseline: 1.5340x; 1.0867x over previous
//
#include <hip/hip_runtime.h>
#include <stdint.h>

typedef unsigned short ushort_t;
typedef __attribute__((__ext_vector_type__(8))) __bf16 bf16x8;
typedef __attribute__((__ext_vector_type__(4))) float f32x4;

__device__ inline ushort_t f2bf(float f) {
    unsigned int u = __float_as_uint(f);
    u = u + 0x7FFFu + ((u >> 16) & 1u);
    return (ushort_t)(u >> 16);
}
__device__ inline float bf2f(ushort_t h) {
    return __uint_as_float(((unsigned int)h) << 16);
}

#define GLOAD16(gp, lp) __builtin_amdgcn_global_load_lds( \
    (__attribute__((address_space(1))) void*)(gp),        \
    (__attribute__((address_space(3))) void*)(lp), 16, 0, 0)

// =====================================================================
// NT GEMM: C[M,N] = A[M,K] * B[N,K]^T  (A,B bf16-as-ushort)
// BM=128, BN in {128,64}, BK in {32,64}. 256 thr = 4 waves (2x2),
// wave tile 64 x (BN/2). MFMA 16x16x32 bf16.
// T3 minimum-2-phase loop (r11-r13 proven): static 4-buffer dbuf,
// manual unroll-by-2, one full-drain barrier per K-tile.
// T2 granule swizzle (rule 21, both-sides involution):
//   GPR=4 (BK=32, 64B rows): s(row) = (row>>1)&3  [r13-proven]
//   GPR=8 (BK=64, 128B rows): s(row) = row&7
//   LDS slot (row,g) holds global granule g^s(row); fragment read f
//   uses slot f^s(row). 16 lanes -> 8 byte-mod-128 positions x2 = free.
// XCD-chunked block swizzle (grids multiples of 8).
// MODE 0: C bf16 (+opt bias) | MODE 3: C f32 + bias
// MODE 4: QKV split epilogue | MODE 5: C = exp(v*scale) bf16 (no atomics)
// =====================================================================
template<int MODE, int BN, int BK>
__global__ __launch_bounds__(256)
void gemm_nt(const ushort_t* __restrict__ A, const ushort_t* __restrict__ B,
             void* __restrict__ Cv, const float* __restrict__ bias,
             int K, int lda, int ldb, int ldc, float scale,
             long long sA, long long sB, long long sC)
{
    constexpr int WN  = BN / 2;
    constexpr int NR  = WN / 16;
    constexpr int GPR = BK / 8;          // 4 (BK=32) or 8 (BK=64)
    constexpr int AG  = 128 * GPR;
    constexpr int BG  = BN * GPR;
    constexpr int ABYTES = 128 * BK * 2;
    constexpr int BBYTES = BN * BK * 2;
    __shared__ __align__(16) char lds[2 * (ABYTES + BBYTES)];
    char* const ldsA0 = lds;
    char* const ldsB0 = lds + ABYTES;
    char* const ldsA1 = lds + ABYTES + BBYTES;
    char* const ldsB1 = lds + 2 * ABYTES + BBYTES;

    const int t = threadIdx.x;

    // ---- XCD-chunked swizzle ----
    const int gx = gridDim.x, gy = gridDim.y;
    const int nwg = gx * gy * gridDim.z;
    int h = (blockIdx.z * gy + blockIdx.y) * gx + blockIdx.x;
    int logical = (h & 7) * (nwg >> 3) + (h >> 3);
    const int bx = logical % gx;
    const int tmp = logical / gx;
    const int by = tmp % gy;
    const int z  = tmp / gy;

    A += (size_t)z * (size_t)sA;
    B += (size_t)z * (size_t)sB;

    const int rowBase = by * 128;
    const int colBase = bx * BN;

    const int w    = t >> 6;
    const int lane = t & 63;
    const int wr = w >> 1, wc = w & 1;
    const int lr = lane & 15, lg = lane >> 4;

    // bank-swizzle involution (constexpr-dispatched on GPR)
    auto swz = [](int row) -> int {
        return (GPR == 8) ? (row & 7) : ((row >> 1) & 3);
    };

    f32x4 acc[4][NR];
#pragma unroll
    for (int i = 0; i < 4; ++i)
#pragma unroll
        for (int j = 0; j < NR; ++j)
            acc[i][j] = (f32x4){0.f, 0.f, 0.f, 0.f};

    auto stage = [&](int kt, char* dA, char* dB) {
#pragma unroll
        for (int i = 0; i < AG / 256; ++i) {
            const int L = i * 256 + t;
            const int row = L / GPR, g = L % GPR;
            const int gs = g ^ swz(row);          // inverse-swizzled source
            GLOAD16(A + (size_t)(rowBase + row) * (size_t)lda + (kt + gs * 8),
                    dA + L * 16);
        }
#pragma unroll
        for (int i = 0; i < BG / 256; ++i) {
            const int L = i * 256 + t;
            const int row = L / GPR, g = L % GPR;
            const int gs = g ^ swz(row);
            GLOAD16(B + (size_t)(colBase + row) * (size_t)ldb + (kt + gs * 8),
                    dB + L * 16);
        }
    };
    auto mfma_phase = [&](const char* la, const char* lb) {
        const bf16x8* A8 = (const bf16x8*)la;
        const bf16x8* B8 = (const bf16x8*)lb;
#pragma unroll
        for (int kk = 0; kk < BK / 32; ++kk) {
            bf16x8 af[4], bq[NR];
#pragma unroll
            for (int mi = 0; mi < 4; ++mi) {
                const int ar = wr * 64 + mi * 16 + lr;
                af[mi] = A8[ar * GPR + ((kk * 4 + lg) ^ swz(ar))];
            }
#pragma unroll
            for (int ni = 0; ni < NR; ++ni) {
                const int br = wc * WN + ni * 16 + lr;
                bq[ni] = B8[br * GPR + ((kk * 4 + lg) ^ swz(br))];
            }
#pragma unroll
            for (int mi = 0; mi < 4; ++mi)
#pragma unroll
                for (int ni = 0; ni < NR; ++ni)
                    acc[mi][ni] = __builtin_amdgcn_mfma_f32_16x16x32_bf16(
                        af[mi], bq[ni], acc[mi][ni], 0, 0, 0);
        }
    };

    const int NT = K / BK;               // even for all K used (8 or 32)
    stage(0, ldsA0, ldsB0);
    __syncthreads();
    for (int it = 0; it < NT; it += 2) {
        stage((it + 1) * BK, ldsA1, ldsB1);   // next tile in flight
        mfma_phase(ldsA0, ldsB0);             // covers part of the drain
        __syncthreads();
        if (it + 2 < NT) stage((it + 2) * BK, ldsA0, ldsB0);
        mfma_phase(ldsA1, ldsB1);
        __syncthreads();
    }

    // ---- epilogue ----
#pragma unroll
    for (int mi = 0; mi < 4; ++mi) {
#pragma unroll
        for (int ni = 0; ni < NR; ++ni) {
#pragma unroll
            for (int r = 0; r < 4; ++r) {
                const int grow = rowBase + wr * 64 + mi * 16 + lg * 4 + r;
                const int gcol = colBase + wc * WN + ni * 16 + lr;
                float v = acc[mi][ni][r] * scale;
                if (MODE == 0) {
                    if (bias) v += bias[gcol];
                    ushort_t* C = (ushort_t*)Cv + (size_t)z * (size_t)sC;
                    C[(size_t)grow * (size_t)ldc + gcol] = f2bf(v);
                } else if (MODE == 3) {
                    float* C = (float*)Cv;
                    C[(size_t)grow * (size_t)ldc + gcol] = v + bias[gcol];
                } else if (MODE == 4) {
                    v += bias[gcol];
                    const int seg = gcol >> 9, c = gcol & 511;
                    ushort_t* C = (ushort_t*)Cv;
                    C[(size_t)seg * 8388608 + (size_t)grow * 512 + c] = f2bf(v);
                } else { // MODE 5: E = exp(score), plain store
                    ushort_t* C = (ushort_t*)Cv + (size_t)z * (size_t)sC;
                    C[(size_t)grow * (size_t)ldc + gcol] = f2bf(__expf(v));
                }
            }
        }
    }
}

// =====================================================================
// V [8][2048][512] -> Vt [8][512][2048]
// =====================================================================
__global__ __launch_bounds__(256)
void transpose_v(const ushort_t* __restrict__ V, ushort_t* __restrict__ Vt)
{
    __shared__ ushort_t lds[64][68];
    const int t = threadIdx.x;
    const int nBase = blockIdx.x * 64;
    const int dBase = blockIdx.y * 64;
    const size_t b = blockIdx.z;
    const ushort_t* src = V + b * 1048576;
    ushort_t* dst = Vt + b * 1048576;
#pragma unroll
    for (int i = 0; i < 2; ++i) {
        int s = i * 256 + t;
        int n = s >> 3, dg = s & 7;
        union { ushort_t h[8]; uint4 u; } p;
        p.u = *(const uint4*)(src + (size_t)(nBase + n) * 512 + dBase + dg * 8);
#pragma unroll
        for (int j = 0; j < 8; ++j) lds[n][dg * 8 + j] = p.h[j];
    }
    __syncthreads();
#pragma unroll
    for (int i = 0; i < 2; ++i) {
        int s = i * 256 + t;
        int d = s >> 3, ng = s & 7;
        union { ushort_t h[8]; uint4 u; } p;
#pragma unroll
        for (int j = 0; j < 8; ++j) p.h[j] = lds[ng * 8 + j][d];
        *(uint4*)(dst + (size_t)(dBase + d) * 2048 + nBase + ng * 8) = p.u;
    }
}

// =====================================================================
__global__ __launch_bounds__(256)
void cvt_bf16(const float* __restrict__ src, ushort_t* __restrict__ dst, int n4)
{
    int i = blockIdx.x * 256 + threadIdx.x;
    if (i >= n4) return;
    float4 v = ((const float4*)src)[i];
    union { ushort_t h[4]; uint2 u; } p;
    p.h[0] = f2bf(v.x); p.h[1] = f2bf(v.y); p.h[2] = f2bf(v.z); p.h[3] = f2bf(v.w);
    ((uint2*)dst)[i] = p.u;
}

__global__ __launch_bounds__(256)
void pack_bias(const float* __restrict__ q, const float* __restrict__ k,
               const float* __restrict__ v, float* __restrict__ dst)
{
    int i = blockIdx.x * 256 + threadIdx.x;
    if (i < 512) dst[i] = q[i];
    else if (i < 1024) dst[i] = k[i - 512];
    else if (i < 1536) dst[i] = v[i - 1024];
}

// =====================================================================
// attn = E/rowsum + intensity, bf16 in-place over E. One block per row;
// the block computes the row sum itself (no atomics).
// =====================================================================
__global__ __launch_bounds__(256)
void norm_add(ushort_t* __restrict__ E, const float* __restrict__ inten)
{
    const int R = blockIdx.x;            // 0..16383
    const int t = threadIdx.x;
    const int w = t >> 6, lane = t & 63;
    ushort_t* erow = E + (size_t)R * 2048;
    const float* irow = inten + (size_t)R * 2048;

    union { ushort_t h[8]; uint4 u; } p;
    p.u = *(const uint4*)(erow + t * 8);
    float f[8];
#pragma unroll
    for (int j = 0; j < 8; ++j) f[j] = bf2f(p.h[j]);

    float s = 0.f;
#pragma unroll
    for (int j = 0; j < 8; ++j) s += f[j];
#pragma unroll
    for (int off = 32; off > 0; off >>= 1) s += __shfl_xor(s, off);

    __shared__ float red[4];
    if (lane == 0) red[w] = s;
    __syncthreads();
    const float inv = 1.f / (red[0] + red[1] + red[2] + red[3]);

    float4 i0 = *(const float4*)(irow + t * 8);
    float4 i1 = *(const float4*)(irow + t * 8 + 4);
    float o[8] = { f[0]*inv + i0.x, f[1]*inv + i0.y, f[2]*inv + i0.z, f[3]*inv + i0.w,
                   f[4]*inv + i1.x, f[5]*inv + i1.y, f[6]*inv + i1.z, f[7]*inv + i1.w };
#pragma unroll
    for (int j = 0; j < 8; ++j) p.h[j] = f2bf(o[j]);
    *(uint4*)(erow + t * 8) = p.u;
}

// =====================================================================
extern "C" void kernel_launch(void* const* d_in, const int* in_sizes, int n_in,
                              void* d_out, int out_size, void* d_ws, size_t ws_size,
                              hipStream_t stream)
{
    const float* X    = (const float*)d_in[0];
    const float* inten= (const float*)d_in[1];
    const float* WQw  = (const float*)d_in[2];
    const float* WQb  = (const float*)d_in[3];
    const float* WKw  = (const float*)d_in[4];
    const float* WKb  = (const float*)d_in[5];
    const float* WVw  = (const float*)d_in[6];
    const float* WVb  = (const float*)d_in[7];
    const float* Wow  = (const float*)d_in[8];
    const float* Wob  = (const float*)d_in[9];
    float* out = (float*)d_out;

    char* ws = (char*)d_ws;
    ushort_t* Vt    = (ushort_t*)(ws + 0);           // 16 MiB
    ushort_t* Wqkv  = (ushort_t*)(ws + 16777216);    // 1536x512 bf16
    ushort_t* Wob2  = (ushort_t*)(ws + 18350080);    // 512x512 bf16
    float*    biasP = (float*)   (ws + 18874368);    // 1536 f32
    ushort_t* QKV   = (ushort_t*)(ws + 19922944);    // Q|K|V row-major, 3x16 MiB
    ushort_t* out1  = (ushort_t*)(ws + 70254592);    // 16 MiB
    ushort_t* Sbf   = (ushort_t*)(ws + 87031808);    // E bf16, 64 MiB
    ushort_t* Xb    = (ushort_t*)(ws + 154140672);   // 16 MiB
    ushort_t* Qb  = QKV;
    ushort_t* Kb  = QKV + 8388608;
    ushort_t* Vrm = QKV + 16777216;

    const float scale = 0.044194173824159216f;       // 1/sqrt(512)

    cvt_bf16<<<dim3(8192), dim3(256), 0, stream>>>(X,   Xb, 2097152);
    cvt_bf16<<<dim3(256),  dim3(256), 0, stream>>>(WQw, Wqkv,          65536);
    cvt_bf16<<<dim3(256),  dim3(256), 0, stream>>>(WKw, Wqkv + 262144, 65536);
    cvt_bf16<<<dim3(256),  dim3(256), 0, stream>>>(WVw, Wqkv + 524288, 65536);
    cvt_bf16<<<dim3(256),  dim3(256), 0, stream>>>(Wow, Wob2,          65536);
    pack_bias<<<dim3(6), dim3(256), 0, stream>>>(WQb, WKb, WVb, biasP);

    // fused QKV projection: [16384,512] @ [1536,512]^T -> Q|K|V row-major
    gemm_nt<4, 128, 64><<<dim3(12, 128, 1), dim3(256), 0, stream>>>(
        Xb, Wqkv, QKV, biasP, 512, 512, 512, 0, 1.f, 0, 0, 0);

    // Vt[b][d][n] = V[b][n][d]
    transpose_v<<<dim3(32, 8, 8), dim3(256), 0, stream>>>(Vrm, Vt);

    // E = exp(scale * Q K^T) bf16, per batch
    gemm_nt<5, 128, 64><<<dim3(16, 16, 8), dim3(256), 0, stream>>>(
        Qb, Kb, Sbf, nullptr, 512, 512, 512, 2048, scale,
        2048LL * 512, 2048LL * 512, 2048LL * 2048);

    // attn = E/rowsum + intensity (bf16, in place, self-reducing)
    norm_add<<<dim3(16384), dim3(256), 0, stream>>>(Sbf, inten);

    // out1 = attn @ Vt^T per batch  [2048,512] bf16
    gemm_nt<0, 64, 64><<<dim3(8, 16, 8), dim3(256), 0, stream>>>(
        Sbf, Vt, out1, nullptr, 2048, 2048, 2048, 512, 1.f,
        2048LL * 2048, 512LL * 2048, 2048LL * 512);

    // out = out1 @ Wo^T + bo  [16384,512] f32
    gemm_nt<3, 64, 64><<<dim3(8, 128, 1), dim3(256), 0, stream>>>(
        out1, Wob2, out, Wob, 512, 512, 512, 512, 1.f, 0, 0, 0);
}

// Round 15
// 193.117 us; speedup vs baseline: 1.6817x; 1.0963x over previous
//
#include <hip/hip_runtime.h>
#include <stdint.h>

typedef unsigned short ushort_t;
typedef __attribute__((__ext_vector_type__(8))) __bf16 bf16x8;
typedef __attribute__((__ext_vector_type__(4))) float f32x4;

__device__ inline ushort_t f2bf(float f) {
    unsigned int u = __float_as_uint(f);
    u = u + 0x7FFFu + ((u >> 16) & 1u);
    return (ushort_t)(u >> 16);
}
__device__ inline float bf2f(ushort_t h) {
    return __uint_as_float(((unsigned int)h) << 16);
}

#define GLOAD16(gp, lp) __builtin_amdgcn_global_load_lds( \
    (__attribute__((address_space(1))) void*)(gp),        \
    (__attribute__((address_space(3))) void*)(lp), 16, 0, 0)

// =====================================================================
// NT GEMM: C[M,N] = A[M,K] * B[N,K]^T  (A,B bf16-as-ushort)
// BM=128, BN=128, BK=64 everywhere (r14-proven config, 64KB LDS dbuf,
// 2 blocks/CU). 256 thr = 4 waves (2x2), wave tile 64x64.
// T3 minimum-2-phase loop (r11-r14 proven): static 4-buffer dbuf.
// T2 granule swizzle (rule 21): GPR=8: s(row)=row&7; slot g holds global
// granule g^s(row); read f uses f^s(row).
// XCD-chunked block swizzle (grids multiples of 8).
// MODE 0: C bf16 (+opt bias) | MODE 3: C f32 + bias
// MODE 4: QKV split epilogue | MODE 5: C = exp(v*scale) bf16 (no atomics)
// =====================================================================
template<int MODE, int BN, int BK>
__global__ __launch_bounds__(256)
void gemm_nt(const ushort_t* __restrict__ A, const ushort_t* __restrict__ B,
             void* __restrict__ Cv, const float* __restrict__ bias,
             int K, int lda, int ldb, int ldc, float scale,
             long long sA, long long sB, long long sC)
{
    constexpr int WN  = BN / 2;
    constexpr int NR  = WN / 16;
    constexpr int GPR = BK / 8;          // 8 for BK=64
    constexpr int AG  = 128 * GPR;
    constexpr int BG  = BN * GPR;
    constexpr int ABYTES = 128 * BK * 2;
    constexpr int BBYTES = BN * BK * 2;
    __shared__ __align__(16) char lds[2 * (ABYTES + BBYTES)];
    char* const ldsA0 = lds;
    char* const ldsB0 = lds + ABYTES;
    char* const ldsA1 = lds + ABYTES + BBYTES;
    char* const ldsB1 = lds + 2 * ABYTES + BBYTES;

    const int t = threadIdx.x;

    // ---- XCD-chunked swizzle ----
    const int gx = gridDim.x, gy = gridDim.y;
    const int nwg = gx * gy * gridDim.z;
    int h = (blockIdx.z * gy + blockIdx.y) * gx + blockIdx.x;
    int logical = (h & 7) * (nwg >> 3) + (h >> 3);
    const int bx = logical % gx;
    const int tmp = logical / gx;
    const int by = tmp % gy;
    const int z  = tmp / gy;

    A += (size_t)z * (size_t)sA;
    B += (size_t)z * (size_t)sB;

    const int rowBase = by * 128;
    const int colBase = bx * BN;

    const int w    = t >> 6;
    const int lane = t & 63;
    const int wr = w >> 1, wc = w & 1;
    const int lr = lane & 15, lg = lane >> 4;

    auto swz = [](int row) -> int {
        return (GPR == 8) ? (row & 7) : ((row >> 1) & 3);
    };

    f32x4 acc[4][NR];
#pragma unroll
    for (int i = 0; i < 4; ++i)
#pragma unroll
        for (int j = 0; j < NR; ++j)
            acc[i][j] = (f32x4){0.f, 0.f, 0.f, 0.f};

    auto stage = [&](int kt, char* dA, char* dB) {
#pragma unroll
        for (int i = 0; i < AG / 256; ++i) {
            const int L = i * 256 + t;
            const int row = L / GPR, g = L % GPR;
            const int gs = g ^ swz(row);
            GLOAD16(A + (size_t)(rowBase + row) * (size_t)lda + (kt + gs * 8),
                    dA + L * 16);
        }
#pragma unroll
        for (int i = 0; i < BG / 256; ++i) {
            const int L = i * 256 + t;
            const int row = L / GPR, g = L % GPR;
            const int gs = g ^ swz(row);
            GLOAD16(B + (size_t)(colBase + row) * (size_t)ldb + (kt + gs * 8),
                    dB + L * 16);
        }
    };
    auto mfma_phase = [&](const char* la, const char* lb) {
        const bf16x8* A8 = (const bf16x8*)la;
        const bf16x8* B8 = (const bf16x8*)lb;
#pragma unroll
        for (int kk = 0; kk < BK / 32; ++kk) {
            bf16x8 af[4], bq[NR];
#pragma unroll
            for (int mi = 0; mi < 4; ++mi) {
                const int ar = wr * 64 + mi * 16 + lr;
                af[mi] = A8[ar * GPR + ((kk * 4 + lg) ^ swz(ar))];
            }
#pragma unroll
            for (int ni = 0; ni < NR; ++ni) {
                const int br = wc * WN + ni * 16 + lr;
                bq[ni] = B8[br * GPR + ((kk * 4 + lg) ^ swz(br))];
            }
#pragma unroll
            for (int mi = 0; mi < 4; ++mi)
#pragma unroll
                for (int ni = 0; ni < NR; ++ni)
                    acc[mi][ni] = __builtin_amdgcn_mfma_f32_16x16x32_bf16(
                        af[mi], bq[ni], acc[mi][ni], 0, 0, 0);
        }
    };

    const int NT = K / BK;               // even for all K used (8 or 32)
    stage(0, ldsA0, ldsB0);
    __syncthreads();
    for (int it = 0; it < NT; it += 2) {
        stage((it + 1) * BK, ldsA1, ldsB1);
        mfma_phase(ldsA0, ldsB0);
        __syncthreads();
        if (it + 2 < NT) stage((it + 2) * BK, ldsA0, ldsB0);
        mfma_phase(ldsA1, ldsB1);
        __syncthreads();
    }

    // ---- epilogue ----
#pragma unroll
    for (int mi = 0; mi < 4; ++mi) {
#pragma unroll
        for (int ni = 0; ni < NR; ++ni) {
#pragma unroll
            for (int r = 0; r < 4; ++r) {
                const int grow = rowBase + wr * 64 + mi * 16 + lg * 4 + r;
                const int gcol = colBase + wc * WN + ni * 16 + lr;
                float v = acc[mi][ni][r] * scale;
                if (MODE == 0) {
                    if (bias) v += bias[gcol];
                    ushort_t* C = (ushort_t*)Cv + (size_t)z * (size_t)sC;
                    C[(size_t)grow * (size_t)ldc + gcol] = f2bf(v);
                } else if (MODE == 3) {
                    float* C = (float*)Cv;
                    C[(size_t)grow * (size_t)ldc + gcol] = v + bias[gcol];
                } else if (MODE == 4) {
                    v += bias[gcol];
                    const int seg = gcol >> 9, c = gcol & 511;
                    ushort_t* C = (ushort_t*)Cv;
                    C[(size_t)seg * 8388608 + (size_t)grow * 512 + c] = f2bf(v);
                } else { // MODE 5
                    ushort_t* C = (ushort_t*)Cv + (size_t)z * (size_t)sC;
                    C[(size_t)grow * (size_t)ldc + gcol] = f2bf(__expf(v));
                }
            }
        }
    }
}

// =====================================================================
// V [8][2048][512] -> Vt [8][512][2048]
// =====================================================================
__global__ __launch_bounds__(256)
void transpose_v(const ushort_t* __restrict__ V, ushort_t* __restrict__ Vt)
{
    __shared__ ushort_t lds[64][68];
    const int t = threadIdx.x;
    const int nBase = blockIdx.x * 64;
    const int dBase = blockIdx.y * 64;
    const size_t b = blockIdx.z;
    const ushort_t* src = V + b * 1048576;
    ushort_t* dst = Vt + b * 1048576;
#pragma unroll
    for (int i = 0; i < 2; ++i) {
        int s = i * 256 + t;
        int n = s >> 3, dg = s & 7;
        union { ushort_t h[8]; uint4 u; } p;
        p.u = *(const uint4*)(src + (size_t)(nBase + n) * 512 + dBase + dg * 8);
#pragma unroll
        for (int j = 0; j < 8; ++j) lds[n][dg * 8 + j] = p.h[j];
    }
    __syncthreads();
#pragma unroll
    for (int i = 0; i < 2; ++i) {
        int s = i * 256 + t;
        int d = s >> 3, ng = s & 7;
        union { ushort_t h[8]; uint4 u; } p;
#pragma unroll
        for (int j = 0; j < 8; ++j) p.h[j] = lds[ng * 8 + j][d];
        *(uint4*)(dst + (size_t)(dBase + d) * 2048 + nBase + ng * 8) = p.u;
    }
}

// =====================================================================
__global__ __launch_bounds__(256)
void cvt_bf16(const float* __restrict__ src, ushort_t* __restrict__ dst, int n4)
{
    int i = blockIdx.x * 256 + threadIdx.x;
    if (i >= n4) return;
    float4 v = ((const float4*)src)[i];
    union { ushort_t h[4]; uint2 u; } p;
    p.h[0] = f2bf(v.x); p.h[1] = f2bf(v.y); p.h[2] = f2bf(v.z); p.h[3] = f2bf(v.w);
    ((uint2*)dst)[i] = p.u;
}

// =====================================================================
// One-shot prologue: convert 4 weight matrices (4x65536 float4 granules)
// and pack the 3 bias vectors. Grid 1025 x 256.
// =====================================================================
__global__ __launch_bounds__(256)
void prep_weights(const float* __restrict__ wq, const float* __restrict__ wk,
                  const float* __restrict__ wv, const float* __restrict__ wo,
                  ushort_t* __restrict__ Wqkv, ushort_t* __restrict__ Wob2,
                  const float* __restrict__ bq, const float* __restrict__ bk,
                  const float* __restrict__ bv, float* __restrict__ biasP)
{
    const int i = blockIdx.x * 256 + threadIdx.x;
    if (i < 262144) {
        const int seg = i >> 16, j = i & 65535;     // 65536 float4 per matrix
        const float* src = (seg == 0) ? wq : (seg == 1) ? wk
                         : (seg == 2) ? wv : wo;
        ushort_t* dst = (seg == 3) ? Wob2 : (Wqkv + seg * 262144);
        float4 v = ((const float4*)src)[j];
        union { ushort_t h[4]; uint2 u; } p;
        p.h[0] = f2bf(v.x); p.h[1] = f2bf(v.y);
        p.h[2] = f2bf(v.z); p.h[3] = f2bf(v.w);
        ((uint2*)dst)[j] = p.u;
    } else {
        const int j = i - 262144;                    // 0..1535 bias pack
        if (j < 512) biasP[j] = bq[j];
        else if (j < 1024) biasP[j] = bk[j - 512];
        else if (j < 1536) biasP[j] = bv[j - 1024];
    }
}

// =====================================================================
// attn = E/rowsum + intensity, bf16 in-place over E. One block per row.
// =====================================================================
__global__ __launch_bounds__(256)
void norm_add(ushort_t* __restrict__ E, const float* __restrict__ inten)
{
    const int R = blockIdx.x;
    const int t = threadIdx.x;
    const int w = t >> 6, lane = t & 63;
    ushort_t* erow = E + (size_t)R * 2048;
    const float* irow = inten + (size_t)R * 2048;

    union { ushort_t h[8]; uint4 u; } p;
    p.u = *(const uint4*)(erow + t * 8);
    float f[8];
#pragma unroll
    for (int j = 0; j < 8; ++j) f[j] = bf2f(p.h[j]);

    float s = 0.f;
#pragma unroll
    for (int j = 0; j < 8; ++j) s += f[j];
#pragma unroll
    for (int off = 32; off > 0; off >>= 1) s += __shfl_xor(s, off);

    __shared__ float red[4];
    if (lane == 0) red[w] = s;
    __syncthreads();
    const float inv = 1.f / (red[0] + red[1] + red[2] + red[3]);

    float4 i0 = *(const float4*)(irow + t * 8);
    float4 i1 = *(const float4*)(irow + t * 8 + 4);
    float o[8] = { f[0]*inv + i0.x, f[1]*inv + i0.y, f[2]*inv + i0.z, f[3]*inv + i0.w,
                   f[4]*inv + i1.x, f[5]*inv + i1.y, f[6]*inv + i1.z, f[7]*inv + i1.w };
#pragma unroll
    for (int j = 0; j < 8; ++j) p.h[j] = f2bf(o[j]);
    *(uint4*)(erow + t * 8) = p.u;
}

// =====================================================================
extern "C" void kernel_launch(void* const* d_in, const int* in_sizes, int n_in,
                              void* d_out, int out_size, void* d_ws, size_t ws_size,
                              hipStream_t stream)
{
    const float* X    = (const float*)d_in[0];
    const float* inten= (const float*)d_in[1];
    const float* WQw  = (const float*)d_in[2];
    const float* WQb  = (const float*)d_in[3];
    const float* WKw  = (const float*)d_in[4];
    const float* WKb  = (const float*)d_in[5];
    const float* WVw  = (const float*)d_in[6];
    const float* WVb  = (const float*)d_in[7];
    const float* Wow  = (const float*)d_in[8];
    const float* Wob  = (const float*)d_in[9];
    float* out = (float*)d_out;

    char* ws = (char*)d_ws;
    ushort_t* Vt    = (ushort_t*)(ws + 0);           // 16 MiB
    ushort_t* Wqkv  = (ushort_t*)(ws + 16777216);    // 1536x512 bf16
    ushort_t* Wob2  = (ushort_t*)(ws + 18350080);    // 512x512 bf16
    float*    biasP = (float*)   (ws + 18874368);    // 1536 f32
    ushort_t* QKV   = (ushort_t*)(ws + 19922944);    // Q|K|V row-major, 3x16 MiB
    ushort_t* out1  = (ushort_t*)(ws + 70254592);    // 16 MiB
    ushort_t* Sbf   = (ushort_t*)(ws + 87031808);    // E bf16, 64 MiB
    ushort_t* Xb    = (ushort_t*)(ws + 154140672);   // 16 MiB
    ushort_t* Qb  = QKV;
    ushort_t* Kb  = QKV + 8388608;
    ushort_t* Vrm = QKV + 16777216;

    const float scale = 0.044194173824159216f;       // 1/sqrt(512)

    cvt_bf16<<<dim3(8192), dim3(256), 0, stream>>>(X, Xb, 2097152);
    prep_weights<<<dim3(1030), dim3(256), 0, stream>>>(
        WQw, WKw, WVw, Wow, Wqkv, Wob2, WQb, WKb, WVb, biasP);

    // fused QKV projection: [16384,512] @ [1536,512]^T -> Q|K|V row-major
    gemm_nt<4, 128, 64><<<dim3(12, 128, 1), dim3(256), 0, stream>>>(
        Xb, Wqkv, QKV, biasP, 512, 512, 512, 0, 1.f, 0, 0, 0);

    // Vt[b][d][n] = V[b][n][d]
    transpose_v<<<dim3(32, 8, 8), dim3(256), 0, stream>>>(Vrm, Vt);

    // E = exp(scale * Q K^T) bf16, per batch
    gemm_nt<5, 128, 64><<<dim3(16, 16, 8), dim3(256), 0, stream>>>(
        Qb, Kb, Sbf, nullptr, 512, 512, 512, 2048, scale,
        2048LL * 512, 2048LL * 512, 2048LL * 2048);

    // attn = E/rowsum + intensity (bf16, in place, self-reducing)
    norm_add<<<dim3(16384), dim3(256), 0, stream>>>(Sbf, inten);

    // out1 = attn @ Vt^T per batch  [2048,512] bf16  (BN=128: 33% less staging)
    gemm_nt<0, 128, 64><<<dim3(4, 16, 8), dim3(256), 0, stream>>>(
        Sbf, Vt, out1, nullptr, 2048, 2048, 2048, 512, 1.f,
        2048LL * 2048, 512LL * 2048, 2048LL * 512);

    // out = out1 @ Wo^T + bo  [16384,512] f32  (BN=128)
    gemm_nt<3, 128, 64><<<dim3(4, 128, 1), dim3(256), 0, stream>>>(
        out1, Wob2, out, Wob, 512, 512, 512, 512, 1.f, 0, 0, 0);
}